// Round 2
// baseline (2858.751 us; speedup 1.0000x reference)
//
#include <hip/hip_runtime.h>
#include <cstddef>

#define TT 2048
#define BB 64
#define DD 256
#define LN_EPS 1e-5f
#define WEPS 1e-4f
#define NS_ITERS 14

__device__ __forceinline__ void fma4x4(float acc[4][4], const float4 a, const float4 bv) {
  acc[0][0] += a.x*bv.x; acc[0][1] += a.x*bv.y; acc[0][2] += a.x*bv.z; acc[0][3] += a.x*bv.w;
  acc[1][0] += a.y*bv.x; acc[1][1] += a.y*bv.y; acc[1][2] += a.y*bv.z; acc[1][3] += a.y*bv.w;
  acc[2][0] += a.z*bv.x; acc[2][1] += a.z*bv.y; acc[2][2] += a.z*bv.z; acc[2][3] += a.z*bv.w;
  acc[3][0] += a.w*bv.x; acc[3][1] += a.w*bv.y; acc[3][2] += a.w*bv.z; acc[3][3] += a.w*bv.w;
}

// ---- K1: per-row LN stats (mean, rstd). One wave per row, 4 rows/block. ----
__global__ __launch_bounds__(256) void ln_stats_kernel(const float* __restrict__ x,
                                                       float* __restrict__ stats) {
  int row  = blockIdx.x * 4 + (threadIdx.x >> 6);
  int lane = threadIdx.x & 63;
  const float4* xr = reinterpret_cast<const float4*>(x + (size_t)row * DD);
  float4 v = xr[lane];
  float s  = v.x + v.y + v.z + v.w;
  float sq = v.x*v.x + v.y*v.y + v.z*v.z + v.w*v.w;
  #pragma unroll
  for (int off = 32; off; off >>= 1) { s += __shfl_xor(s, off); sq += __shfl_xor(sq, off); }
  if (lane == 0) {
    float mean = s * (1.f/DD);
    float var  = fmaxf(sq * (1.f/DD) - mean*mean, 0.f);
    stats[2*row]   = mean;
    stats[2*row+1] = rsqrtf(var + LN_EPS);
  }
}

// ---- K2a: partial column sums of (x-mean)*rstd per batch (deterministic 2-stage) ----
__global__ __launch_bounds__(256) void mu_partial_kernel(const float* __restrict__ x,
                                                         const float* __restrict__ stats,
                                                         float* __restrict__ part) {
  int c = blockIdx.x;   // 0..15
  int b = blockIdx.y;
  int d = threadIdx.x;  // 0..255
  const int rowsPer = TT / 16;
  int t0 = c * rowsPer;
  const float* xp = x + ((size_t)b*TT + t0) * DD + d;
  const float* st = stats + ((size_t)b*TT + t0) * 2;
  float s = 0.f;
  for (int t = 0; t < rowsPer; ++t)
    s += (xp[(size_t)t*DD] - st[2*t]) * st[2*t+1];
  part[((size_t)c*BB + b)*DD + d] = s;
}

// ---- K2b: mu = gamma * (sum of partials)/T + beta ----
__global__ __launch_bounds__(256) void mu_finalize_kernel(const float* __restrict__ part,
                                                          const float* __restrict__ gamma,
                                                          const float* __restrict__ beta,
                                                          float* __restrict__ mu) {
  int b = blockIdx.x;
  int d = threadIdx.x;
  float s = 0.f;
  #pragma unroll
  for (int c = 0; c < 16; ++c) s += part[((size_t)c*BB + b)*DD + d];
  mu[b*DD + d] = gamma[d] * s * (1.f/TT) + beta[d];
}

// ---- K3: cov = (A^T A - T mu mu^T)/(T-1) + eps I, A = LN(x) on-the-fly.
//      Symmetric: only upper tile-pairs; also per-(b,tile) Frobenius^2 partials. ----
__global__ __launch_bounds__(256) void cov_kernel(const float* __restrict__ x,
    const float* __restrict__ stats, const float* __restrict__ gamma,
    const float* __restrict__ beta, const float* __restrict__ mu,
    float* __restrict__ C, float* __restrict__ ssqp) {
  int tile = blockIdx.x;  // 0..9 upper-triangular pair
  int b = blockIdx.y;
  int p = 0, t = tile;
  while (t >= 4 - p) { t -= (4 - p); ++p; }
  int q = p + t;
  int i0 = p * 64, j0 = q * 64;
  bool diag = (i0 == j0);

  __shared__ float Ai[32][64];
  __shared__ float Aj[32][64];
  int tid = threadIdx.x;
  int ti = tid >> 4, tj = tid & 15;
  float acc[4][4] = {};
  const float* xb  = x + (size_t)b*TT*DD;
  const float* stb = stats + (size_t)b*TT*2;

  for (int k0 = 0; k0 < TT; k0 += 32) {
    #pragma unroll
    for (int l = 0; l < 8; ++l) {          // FIX: 8*256 = 2048 = 32x64 elements
      int e = tid + l*256;
      int r = e >> 6, c = e & 63;
      float mean = stb[2*(k0+r)], rstd = stb[2*(k0+r)+1];
      float gi = gamma[i0+c], bi = beta[i0+c];
      Ai[r][c] = (xb[(size_t)(k0+r)*DD + i0 + c] - mean) * rstd * gi + bi;
      if (!diag) {
        float gj = gamma[j0+c], bj = beta[j0+c];
        Aj[r][c] = (xb[(size_t)(k0+r)*DD + j0 + c] - mean) * rstd * gj + bj;
      }
    }
    __syncthreads();
    const float (*Bsrc)[64] = (const float (*)[64])(diag ? Ai : Aj);
    #pragma unroll
    for (int k = 0; k < 32; ++k) {
      float4 a  = *(const float4*)&Ai[k][ti*4];
      float4 bv = *(const float4*)&Bsrc[k][tj*4];
      fma4x4(acc, a, bv);
    }
    __syncthreads();
  }

  float* Cb = C + (size_t)b*DD*DD;
  const float* mub = mu + b*DD;
  const float invTm1 = 1.f / (float)(TT - 1);
  const float w = diag ? 1.f : 2.f;
  float lssq = 0.f;
  #pragma unroll
  for (int ii = 0; ii < 4; ++ii) {
    int i = i0 + ti*4 + ii;
    float mi = mub[i];
    float vrow[4];
    #pragma unroll
    for (int jj = 0; jj < 4; ++jj) {
      int j = j0 + tj*4 + jj;
      float v = (acc[ii][jj] - (float)TT * mi * mub[j]) * invTm1;
      if (i == j) v += WEPS;
      vrow[jj] = v;
      lssq += w * v * v;
      if (!diag) Cb[(size_t)j*DD + i] = v;
    }
    *(float4*)&Cb[(size_t)i*DD + j0 + tj*4] = make_float4(vrow[0], vrow[1], vrow[2], vrow[3]);
  }
  // block-reduce lssq -> ssqp[b*10+tile]
  #pragma unroll
  for (int off = 32; off; off >>= 1) lssq += __shfl_xor(lssq, off);
  __shared__ float red[4];
  if ((tid & 63) == 0) red[tid >> 6] = lssq;
  __syncthreads();
  if (tid == 0) ssqp[b*10 + tile] = red[0] + red[1] + red[2] + red[3];
}

// ---- K4: Y = C/||C||_F (in place), Z = I ----
__global__ __launch_bounds__(256) void ns_init_kernel(float* __restrict__ Y,
                                                      float* __restrict__ Z,
                                                      const float* __restrict__ ssqp) {
  int b = blockIdx.y;
  int e = blockIdx.x * 256 + threadIdx.x;  // 0..65535
  float ssq = 0.f;
  #pragma unroll
  for (int t = 0; t < 10; ++t) ssq += ssqp[b*10 + t];
  float invs = rsqrtf(ssq);  // 1/||C||_F
  size_t idx = (size_t)b*DD*DD + e;
  Y[idx] *= invs;
  Z[idx] = ((e >> 8) == (e & 255)) ? 1.f : 0.f;
}

// ---- K5: batched C = alpha*A*B + diagBeta*I  (256x256x256 per batch) ----
__global__ __launch_bounds__(256) void bgemm_kernel(const float* __restrict__ A,
    const float* __restrict__ B, float* __restrict__ Cc, float alpha, float diagBeta) {
  int tile = blockIdx.x;  // 16 tiles of 64x64
  int b = blockIdx.y;
  int i0 = (tile >> 2) * 64, j0 = (tile & 3) * 64;
  __shared__ float As[32][68];  // [k][i] transposed, padded
  __shared__ float Bs[32][64];  // [k][j]
  int tid = threadIdx.x;
  int ti = tid >> 4, tj = tid & 15;
  float acc[4][4] = {};
  const float* Ab = A + (size_t)b*DD*DD;
  const float* Bb = B + (size_t)b*DD*DD;
  for (int k0 = 0; k0 < DD; k0 += 32) {
    #pragma unroll
    for (int l = 0; l < 8; ++l) {
      int e = tid + l*256;
      int r = e >> 5, c = e & 31;       // A: 64 rows x 32 k
      As[c][r] = Ab[(size_t)(i0 + r)*DD + k0 + c];
      int r2 = e >> 6, c2 = e & 63;     // B: 32 k x 64 cols
      Bs[r2][c2] = Bb[(size_t)(k0 + r2)*DD + j0 + c2];
    }
    __syncthreads();
    #pragma unroll
    for (int k = 0; k < 32; ++k) {
      float4 a  = *(const float4*)&As[k][ti*4];
      float4 bv = *(const float4*)&Bs[k][tj*4];
      fma4x4(acc, a, bv);
    }
    __syncthreads();
  }
  float* Cb = Cc + (size_t)b*DD*DD;
  #pragma unroll
  for (int ii = 0; ii < 4; ++ii) {
    int i = i0 + ti*4 + ii;
    float v0 = alpha*acc[ii][0], v1 = alpha*acc[ii][1], v2 = alpha*acc[ii][2], v3 = alpha*acc[ii][3];
    int jb = j0 + tj*4;
    if (i - jb >= 0 && i - jb < 4) {
      if (i == jb+0) v0 += diagBeta;
      if (i == jb+1) v1 += diagBeta;
      if (i == jb+2) v2 += diagBeta;
      if (i == jb+3) v3 += diagBeta;
    }
    *(float4*)&Cb[(size_t)i*DD + jb] = make_float4(v0, v1, v2, v3);
  }
}

// ---- K6: out = (LN(x) - mu) @ (Z / sqrt(s)),  s = ||C||_F ----
__global__ __launch_bounds__(256) void out_kernel(const float* __restrict__ x,
    const float* __restrict__ stats, const float* __restrict__ gamma,
    const float* __restrict__ beta, const float* __restrict__ mu,
    const float* __restrict__ Z, const float* __restrict__ ssqp,
    float* __restrict__ out) {
  int tile = blockIdx.x;  // 0..127 : 32 t-tiles x 4 f-tiles
  int b = blockIdx.y;
  int t0 = (tile >> 2) * 64, f0 = (tile & 3) * 64;
  __shared__ float As[32][68];
  __shared__ float Bs[32][64];
  int tid = threadIdx.x;
  int ti = tid >> 4, tj = tid & 15;
  float acc[4][4] = {};
  const float* xb  = x + (size_t)b*TT*DD;
  const float* stb = stats + (size_t)b*TT*2;
  const float* mub = mu + b*DD;
  const float* Zb  = Z + (size_t)b*DD*DD;
  for (int k0 = 0; k0 < DD; k0 += 32) {
    #pragma unroll
    for (int l = 0; l < 8; ++l) {
      int e = tid + l*256;
      int r = e >> 5, c = e & 31;
      int trow = t0 + r, d = k0 + c;
      float xn = (xb[(size_t)trow*DD + d] - stb[2*trow]) * stb[2*trow+1] * gamma[d] + beta[d];
      As[c][r] = xn - mub[d];
      int r2 = e >> 6, c2 = e & 63;
      Bs[r2][c2] = Zb[(size_t)(k0 + r2)*DD + f0 + c2];
    }
    __syncthreads();
    #pragma unroll
    for (int k = 0; k < 32; ++k) {
      float4 a  = *(const float4*)&As[k][ti*4];
      float4 bv = *(const float4*)&Bs[k][tj*4];
      fma4x4(acc, a, bv);
    }
    __syncthreads();
  }
  float ssq = 0.f;
  #pragma unroll
  for (int t = 0; t < 10; ++t) ssq += ssqp[b*10 + t];
  float rs = rsqrtf(sqrtf(ssq));  // s^{-1/2} = ssq^{-1/4}
  float* ob = out + (size_t)b*TT*DD;
  #pragma unroll
  for (int ii = 0; ii < 4; ++ii) {
    int trow = t0 + ti*4 + ii;
    *(float4*)&ob[(size_t)trow*DD + f0 + tj*4] =
      make_float4(acc[ii][0]*rs, acc[ii][1]*rs, acc[ii][2]*rs, acc[ii][3]*rs);
  }
}

extern "C" void kernel_launch(void* const* d_in, const int* in_sizes, int n_in,
                              void* d_out, int out_size, void* d_ws, size_t ws_size,
                              hipStream_t stream) {
  const float* x     = (const float*)d_in[0];
  const float* gamma = (const float*)d_in[1];
  const float* beta  = (const float*)d_in[2];
  float* out = (float*)d_out;

  float* wsf   = (float*)d_ws;
  float* stats = wsf;                  // 2*BB*TT            = 262144 floats
  float* part  = wsf + 262144;         // 16*BB*DD           = 262144
  float* mu    = wsf + 524288;         // BB*DD              = 16384
  float* ssqp  = wsf + 540672;         // BB*10 (+pad)
  float* buf0  = wsf + 544768;         // 4 x BB*DD*DD (16 MB each)
  const size_t MAT = (size_t)BB*DD*DD; // 4194304 floats
  float* buf1 = buf0 + MAT;
  float* buf2 = buf1 + MAT;
  float* buf3 = buf2 + MAT;

  ln_stats_kernel<<<BB*TT/4, 256, 0, stream>>>(x, stats);
  mu_partial_kernel<<<dim3(16, BB), 256, 0, stream>>>(x, stats, part);
  mu_finalize_kernel<<<BB, 256, 0, stream>>>(part, gamma, beta, mu);
  cov_kernel<<<dim3(10, BB), 256, 0, stream>>>(x, stats, gamma, beta, mu, buf0, ssqp);
  ns_init_kernel<<<dim3(256, BB), 256, 0, stream>>>(buf0, buf1, ssqp);

  // Coupled Newton-Schulz with 4-buffer rotation:
  //   M = 3I - Z*Y;  Ynew = 0.5*Y*M (-> spare);  Znew = 0.5*M*Z (-> dead Y buffer)
  float* Y = buf0;
  float* Zm = buf1;
  float* M = buf2;
  float* S = buf3;
  for (int it = 0; it < NS_ITERS; ++it) {
    bgemm_kernel<<<dim3(16, BB), 256, 0, stream>>>(Zm, Y, M, -1.f, 3.f);
    bgemm_kernel<<<dim3(16, BB), 256, 0, stream>>>(Y, M, S, 0.5f, 0.f);
    bgemm_kernel<<<dim3(16, BB), 256, 0, stream>>>(M, Zm, Y, 0.5f, 0.f);
    float* oldY = Y; float* oldZ = Zm;
    Y = S; Zm = oldY; S = oldZ;
  }

  out_kernel<<<dim3(128, BB), 256, 0, stream>>>(x, stats, gamma, beta, mu, Zm, ssqp, out);
}

// Round 3
// 1458.445 us; speedup vs baseline: 1.9601x; 1.9601x over previous
//
#include <hip/hip_runtime.h>
#include <cstddef>

#define TT 2048
#define BB 64
#define DD 256
#define LN_EPS 1e-5f
#define WEPS 1e-4f
#define NS_ITERS 12

typedef __attribute__((ext_vector_type(8))) short bf16x8;
typedef __attribute__((ext_vector_type(4))) float f32x4;

__device__ __forceinline__ unsigned short f2bf(float f) {
  unsigned u = __float_as_uint(f);
  return (unsigned short)((u + 0x7FFFu + ((u >> 16) & 1u)) >> 16);
}
__device__ __forceinline__ float bf2f(unsigned short h) {
  return __uint_as_float(((unsigned)h) << 16);
}

__device__ __forceinline__ void fma4x4(float acc[4][4], const float4 a, const float4 bv) {
  acc[0][0] += a.x*bv.x; acc[0][1] += a.x*bv.y; acc[0][2] += a.x*bv.z; acc[0][3] += a.x*bv.w;
  acc[1][0] += a.y*bv.x; acc[1][1] += a.y*bv.y; acc[1][2] += a.y*bv.z; acc[1][3] += a.y*bv.w;
  acc[2][0] += a.z*bv.x; acc[2][1] += a.z*bv.y; acc[2][2] += a.z*bv.z; acc[2][3] += a.z*bv.w;
  acc[3][0] += a.w*bv.x; acc[3][1] += a.w*bv.y; acc[3][2] += a.w*bv.z; acc[3][3] += a.w*bv.w;
}

// ---- K1: per-row LN stats (mean, rstd) ----
__global__ __launch_bounds__(256) void ln_stats_kernel(const float* __restrict__ x,
                                                       float* __restrict__ stats) {
  int row  = blockIdx.x * 4 + (threadIdx.x >> 6);
  int lane = threadIdx.x & 63;
  const float4* xr = reinterpret_cast<const float4*>(x + (size_t)row * DD);
  float4 v = xr[lane];
  float s  = v.x + v.y + v.z + v.w;
  float sq = v.x*v.x + v.y*v.y + v.z*v.z + v.w*v.w;
  #pragma unroll
  for (int off = 32; off; off >>= 1) { s += __shfl_xor(s, off); sq += __shfl_xor(sq, off); }
  if (lane == 0) {
    float mean = s * (1.f/DD);
    float var  = fmaxf(sq * (1.f/DD) - mean*mean, 0.f);
    stats[2*row]   = mean;
    stats[2*row+1] = rsqrtf(var + LN_EPS);
  }
}

// ---- K2a/K2b: column means of LN(x) per batch ----
__global__ __launch_bounds__(256) void mu_partial_kernel(const float* __restrict__ x,
                                                         const float* __restrict__ stats,
                                                         float* __restrict__ part) {
  int c = blockIdx.x;
  int b = blockIdx.y;
  int d = threadIdx.x;
  const int rowsPer = TT / 16;
  int t0 = c * rowsPer;
  const float* xp = x + ((size_t)b*TT + t0) * DD + d;
  const float* st = stats + ((size_t)b*TT + t0) * 2;
  float s = 0.f;
  for (int t = 0; t < rowsPer; ++t)
    s += (xp[(size_t)t*DD] - st[2*t]) * st[2*t+1];
  part[((size_t)c*BB + b)*DD + d] = s;
}

__global__ __launch_bounds__(256) void mu_finalize_kernel(const float* __restrict__ part,
                                                          const float* __restrict__ gamma,
                                                          const float* __restrict__ beta,
                                                          float* __restrict__ mu) {
  int b = blockIdx.x;
  int d = threadIdx.x;
  float s = 0.f;
  #pragma unroll
  for (int c = 0; c < 16; ++c) s += part[((size_t)c*BB + b)*DD + d];
  mu[b*DD + d] = gamma[d] * s * (1.f/TT) + beta[d];
}

// ---- K3: cov -> split hi/lo bf16 pair + Frobenius^2 partials ----
__global__ __launch_bounds__(256) void cov_kernel(const float* __restrict__ x,
    const float* __restrict__ stats, const float* __restrict__ gamma,
    const float* __restrict__ beta, const float* __restrict__ mu,
    unsigned short* __restrict__ Chh, unsigned short* __restrict__ Cll,
    float* __restrict__ ssqp) {
  int tile = blockIdx.x;  // 0..9 upper-triangular pair
  int b = blockIdx.y;
  int p = 0, t = tile;
  while (t >= 4 - p) { t -= (4 - p); ++p; }
  int q = p + t;
  int i0 = p * 64, j0 = q * 64;
  bool diag = (i0 == j0);

  __shared__ float Ai[32][64];
  __shared__ float Aj[32][64];
  int tid = threadIdx.x;
  int ti = tid >> 4, tj = tid & 15;
  float acc[4][4] = {};
  const float* xb  = x + (size_t)b*TT*DD;
  const float* stb = stats + (size_t)b*TT*2;

  for (int k0 = 0; k0 < TT; k0 += 32) {
    #pragma unroll
    for (int l = 0; l < 8; ++l) {
      int e = tid + l*256;
      int r = e >> 6, c = e & 63;
      float mean = stb[2*(k0+r)], rstd = stb[2*(k0+r)+1];
      Ai[r][c] = (xb[(size_t)(k0+r)*DD + i0 + c] - mean) * rstd * gamma[i0+c] + beta[i0+c];
      if (!diag)
        Aj[r][c] = (xb[(size_t)(k0+r)*DD + j0 + c] - mean) * rstd * gamma[j0+c] + beta[j0+c];
    }
    __syncthreads();
    const float (*Bsrc)[64] = (const float (*)[64])(diag ? Ai : Aj);
    #pragma unroll
    for (int k = 0; k < 32; ++k) {
      float4 a  = *(const float4*)&Ai[k][ti*4];
      float4 bv = *(const float4*)&Bsrc[k][tj*4];
      fma4x4(acc, a, bv);
    }
    __syncthreads();
  }

  unsigned short* Chb = Chh + (size_t)b*DD*DD;
  unsigned short* Clb = Cll + (size_t)b*DD*DD;
  const float* mub = mu + b*DD;
  const float invTm1 = 1.f / (float)(TT - 1);
  const float w = diag ? 1.f : 2.f;
  float lssq = 0.f;
  #pragma unroll
  for (int ii = 0; ii < 4; ++ii) {
    int i = i0 + ti*4 + ii;
    float mi = mub[i];
    unsigned short h4[4], l4[4];
    #pragma unroll
    for (int jj = 0; jj < 4; ++jj) {
      int j = j0 + tj*4 + jj;
      float v = (acc[ii][jj] - (float)TT * mi * mub[j]) * invTm1;
      if (i == j) v += WEPS;
      lssq += w * v * v;
      h4[jj] = f2bf(v);
      l4[jj] = f2bf(v - bf2f(h4[jj]));
      if (!diag) { Chb[(size_t)j*DD + i] = h4[jj]; Clb[(size_t)j*DD + i] = l4[jj]; }
    }
    *(ushort4*)&Chb[(size_t)i*DD + j0 + tj*4] = make_ushort4(h4[0],h4[1],h4[2],h4[3]);
    *(ushort4*)&Clb[(size_t)i*DD + j0 + tj*4] = make_ushort4(l4[0],l4[1],l4[2],l4[3]);
  }
  #pragma unroll
  for (int off = 32; off; off >>= 1) lssq += __shfl_xor(lssq, off);
  __shared__ float red[4];
  if ((tid & 63) == 0) red[tid >> 6] = lssq;
  __syncthreads();
  if (tid == 0) ssqp[b*10 + tile] = red[0] + red[1] + red[2] + red[3];
}

// ---- K4: Y = C/||C||_F (re-split in place), Z = I ----
__global__ __launch_bounds__(256) void ns_init_kernel(unsigned short* __restrict__ Yh,
    unsigned short* __restrict__ Yl, unsigned short* __restrict__ Zh,
    unsigned short* __restrict__ Zl, const float* __restrict__ ssqp) {
  int b = blockIdx.y;
  int e = blockIdx.x * 256 + threadIdx.x;
  float ssq = 0.f;
  #pragma unroll
  for (int t = 0; t < 10; ++t) ssq += ssqp[b*10 + t];
  float invs = rsqrtf(ssq);
  size_t idx = (size_t)b*DD*DD + e;
  float y = (bf2f(Yh[idx]) + bf2f(Yl[idx])) * invs;
  unsigned short h = f2bf(y);
  Yh[idx] = h;
  Yl[idx] = f2bf(y - bf2f(h));
  bool dg = (e >> 8) == (e & 255);
  Zh[idx] = dg ? (unsigned short)0x3F80 : (unsigned short)0;
  Zl[idx] = 0;
}

// ---- K5: MFMA split-bf16 batched GEMM: C = alpha*A*B + diagBeta*I ----
// All operands SYMMETRIC (NS iterates commute) -> layout-transpose-robust.
__global__ __launch_bounds__(256) void bgemm_mfma(
    const unsigned short* __restrict__ Ah, const unsigned short* __restrict__ Al,
    const unsigned short* __restrict__ Bh, const unsigned short* __restrict__ Bl,
    unsigned short* __restrict__ Ch, unsigned short* __restrict__ Cl,
    float alpha, float diagBeta) {
  __shared__ unsigned short sm[4 * 64 * 64];   // sAh,sAl,sBh,sBl (8KB each)
  unsigned short* sAh = sm;
  unsigned short* sAl = sm + 4096;
  unsigned short* sBh = sm + 8192;
  unsigned short* sBl = sm + 12288;

  const int tid = threadIdx.x;
  const int b = blockIdx.y;
  const int i0 = (blockIdx.x >> 2) * 64, j0 = (blockIdx.x & 3) * 64;
  const size_t mb = (size_t)b * DD * DD;
  const int wave = tid >> 6, lane = tid & 63;
  const int lr = lane & 15, lg = lane >> 4;
  const int r0 = tid >> 3;   // staging row 0..31 (+32 for p=1)
  const int c0 = tid & 7;    // 16B chunk in row

  f32x4 acc[4] = {};

  for (int k0 = 0; k0 < DD; k0 += 64) {
    #pragma unroll
    for (int p = 0; p < 2; ++p) {
      int row = r0 + p * 32;
      int ld = row * 64 + ((c0 ^ (row & 7)) * 8);   // XOR-swizzled
      size_t ga = mb + (size_t)(i0 + row) * DD + k0 + c0 * 8;
      size_t gb = mb + (size_t)(j0 + row) * DD + k0 + c0 * 8;  // B symmetric: rows==cols
      *(bf16x8*)&sAh[ld] = *(const bf16x8*)&Ah[ga];
      *(bf16x8*)&sAl[ld] = *(const bf16x8*)&Al[ga];
      *(bf16x8*)&sBh[ld] = *(const bf16x8*)&Bh[gb];
      *(bf16x8*)&sBl[ld] = *(const bf16x8*)&Bl[gb];
    }
    __syncthreads();
    #pragma unroll
    for (int ks = 0; ks < 2; ++ks) {
      int rowA = wave * 16 + lr;
      int cc = ks * 4 + lg;
      int aoff = rowA * 64 + ((cc ^ (rowA & 7)) * 8);
      bf16x8 ahi = *(const bf16x8*)&sAh[aoff];
      bf16x8 alo = *(const bf16x8*)&sAl[aoff];
      #pragma unroll
      for (int n = 0; n < 4; ++n) {
        int rowB = n * 16 + lr;
        int boff = rowB * 64 + ((cc ^ (rowB & 7)) * 8);
        bf16x8 bhi = *(const bf16x8*)&sBh[boff];
        bf16x8 blo = *(const bf16x8*)&sBl[boff];
        acc[n] = __builtin_amdgcn_mfma_f32_16x16x32_bf16(ahi, bhi, acc[n], 0, 0, 0);
        acc[n] = __builtin_amdgcn_mfma_f32_16x16x32_bf16(ahi, blo, acc[n], 0, 0, 0);
        acc[n] = __builtin_amdgcn_mfma_f32_16x16x32_bf16(alo, bhi, acc[n], 0, 0, 0);
      }
    }
    __syncthreads();
  }

  // epilogue: frags -> LDS f32 [64][65] -> coalesced split stores
  float* sC = (float*)sm;
  #pragma unroll
  for (int n = 0; n < 4; ++n)
    #pragma unroll
    for (int r = 0; r < 4; ++r)
      sC[(wave * 16 + lg * 4 + r) * 65 + n * 16 + lr] = acc[n][r];
  __syncthreads();
  int row = tid >> 2, cb = (tid & 3) * 16;
  unsigned short hv[16], lv[16];
  #pragma unroll
  for (int e = 0; e < 16; ++e) {
    float v = alpha * sC[row * 65 + cb + e];
    if (i0 + row == j0 + cb + e) v += diagBeta;
    hv[e] = f2bf(v);
    lv[e] = f2bf(v - bf2f(hv[e]));
  }
  size_t go = mb + (size_t)(i0 + row) * DD + j0 + cb;
  *(bf16x8*)&Ch[go]     = *(bf16x8*)&hv[0];
  *(bf16x8*)&Ch[go + 8] = *(bf16x8*)&hv[8];
  *(bf16x8*)&Cl[go]     = *(bf16x8*)&lv[0];
  *(bf16x8*)&Cl[go + 8] = *(bf16x8*)&lv[8];
}

// ---- K6: out = (LN(x) - mu) @ ((Zh+Zl) * ssq^{-1/4}) ----
__global__ __launch_bounds__(256) void out_kernel(const float* __restrict__ x,
    const float* __restrict__ stats, const float* __restrict__ gamma,
    const float* __restrict__ beta, const float* __restrict__ mu,
    const unsigned short* __restrict__ Zh, const unsigned short* __restrict__ Zl,
    const float* __restrict__ ssqp, float* __restrict__ out) {
  int tile = blockIdx.x;
  int b = blockIdx.y;
  int t0 = (tile >> 2) * 64, f0 = (tile & 3) * 64;
  __shared__ float As[32][68];
  __shared__ float Bs[32][64];
  int tid = threadIdx.x;
  int ti = tid >> 4, tj = tid & 15;
  float acc[4][4] = {};
  const float* xb  = x + (size_t)b*TT*DD;
  const float* stb = stats + (size_t)b*TT*2;
  const float* mub = mu + b*DD;
  const unsigned short* Zhb = Zh + (size_t)b*DD*DD;
  const unsigned short* Zlb = Zl + (size_t)b*DD*DD;
  for (int k0 = 0; k0 < DD; k0 += 32) {
    #pragma unroll
    for (int l = 0; l < 8; ++l) {
      int e = tid + l*256;
      int r = e >> 5, c = e & 31;
      int trow = t0 + r, d = k0 + c;
      float xn = (xb[(size_t)trow*DD + d] - stb[2*trow]) * stb[2*trow+1] * gamma[d] + beta[d];
      As[c][r] = xn - mub[d];
      int r2 = e >> 6, c2 = e & 63;
      size_t zi = (size_t)(k0 + r2)*DD + f0 + c2;
      Bs[r2][c2] = bf2f(Zhb[zi]) + bf2f(Zlb[zi]);
    }
    __syncthreads();
    #pragma unroll
    for (int k = 0; k < 32; ++k) {
      float4 a  = *(const float4*)&As[k][ti*4];
      float4 bv = *(const float4*)&Bs[k][tj*4];
      fma4x4(acc, a, bv);
    }
    __syncthreads();
  }
  float ssq = 0.f;
  #pragma unroll
  for (int t = 0; t < 10; ++t) ssq += ssqp[b*10 + t];
  float rs = rsqrtf(sqrtf(ssq));
  float* ob = out + (size_t)b*TT*DD;
  #pragma unroll
  for (int ii = 0; ii < 4; ++ii) {
    int trow = t0 + ti*4 + ii;
    *(float4*)&ob[(size_t)trow*DD + f0 + tj*4] =
      make_float4(acc[ii][0]*rs, acc[ii][1]*rs, acc[ii][2]*rs, acc[ii][3]*rs);
  }
}

extern "C" void kernel_launch(void* const* d_in, const int* in_sizes, int n_in,
                              void* d_out, int out_size, void* d_ws, size_t ws_size,
                              hipStream_t stream) {
  const float* x     = (const float*)d_in[0];
  const float* gamma = (const float*)d_in[1];
  const float* beta  = (const float*)d_in[2];
  float* out = (float*)d_out;

  float* wsf   = (float*)d_ws;
  float* stats = wsf;                  // 262144 floats
  float* part  = wsf + 262144;         // 262144
  float* mu    = wsf + 524288;         // 16384
  float* ssqp  = wsf + 540672;         // 4096 (pad)
  unsigned short* nsb = (unsigned short*)(wsf + 544768);
  const size_t MATU = (size_t)BB * DD * DD;      // 4194304 ushorts per component
  unsigned short *H[4], *L[4];
  for (int k = 0; k < 4; ++k) { H[k] = nsb + (size_t)k * 2 * MATU; L[k] = H[k] + MATU; }

  ln_stats_kernel<<<BB*TT/4, 256, 0, stream>>>(x, stats);
  mu_partial_kernel<<<dim3(16, BB), 256, 0, stream>>>(x, stats, part);
  mu_finalize_kernel<<<BB, 256, 0, stream>>>(part, gamma, beta, mu);
  cov_kernel<<<dim3(10, BB), 256, 0, stream>>>(x, stats, gamma, beta, mu, H[0], L[0], ssqp);
  ns_init_kernel<<<dim3(256, BB), 256, 0, stream>>>(H[0], L[0], H[1], L[1], ssqp);

  int y = 0, z = 1, m = 2, s = 3;
  for (int it = 0; it < NS_ITERS; ++it) {
    bgemm_mfma<<<dim3(16, BB), 256, 0, stream>>>(H[z], L[z], H[y], L[y], H[m], L[m], -1.f, 3.f);
    bgemm_mfma<<<dim3(16, BB), 256, 0, stream>>>(H[y], L[y], H[m], L[m], H[s], L[s], 0.5f, 0.f);
    bgemm_mfma<<<dim3(16, BB), 256, 0, stream>>>(H[m], L[m], H[z], L[z], H[y], L[y], 0.5f, 0.f);
    int oy = y, oz = z;
    y = s; z = oy; s = oz;
  }

  out_kernel<<<dim3(128, BB), 256, 0, stream>>>(x, stats, gamma, beta, mu, H[z], L[z], ssqp, out);
}

// Round 4
// 836.483 us; speedup vs baseline: 3.4176x; 1.7435x over previous
//
#include <hip/hip_runtime.h>
#include <cstddef>

#define TT 2048
#define BB 64
#define DD 256
#define LN_EPS 1e-5f
#define WEPS 1e-4f
#define NS_ITERS 10

typedef __attribute__((ext_vector_type(8))) short bf16x8;
typedef __attribute__((ext_vector_type(4))) float f32x4;

__device__ __forceinline__ unsigned short f2bf(float f) {
  unsigned u = __float_as_uint(f);
  return (unsigned short)((u + 0x7FFFu + ((u >> 16) & 1u)) >> 16);
}
__device__ __forceinline__ float bf2f(unsigned short h) {
  return __uint_as_float(((unsigned)h) << 16);
}

// ---- K1: per-row LN stats (mean, rstd) ----
__global__ __launch_bounds__(256) void ln_stats_kernel(const float* __restrict__ x,
                                                       float* __restrict__ stats) {
  int row  = blockIdx.x * 4 + (threadIdx.x >> 6);
  int lane = threadIdx.x & 63;
  const float4* xr = reinterpret_cast<const float4*>(x + (size_t)row * DD);
  float4 v = xr[lane];
  float s  = v.x + v.y + v.z + v.w;
  float sq = v.x*v.x + v.y*v.y + v.z*v.z + v.w*v.w;
  #pragma unroll
  for (int off = 32; off; off >>= 1) { s += __shfl_xor(s, off); sq += __shfl_xor(sq, off); }
  if (lane == 0) {
    float mean = s * (1.f/DD);
    float var  = fmaxf(sq * (1.f/DD) - mean*mean, 0.f);
    stats[2*row]   = mean;
    stats[2*row+1] = rsqrtf(var + LN_EPS);
  }
}

// ---- K2a/K2b: column means of LN(x) per batch ----
__global__ __launch_bounds__(256) void mu_partial_kernel(const float* __restrict__ x,
                                                         const float* __restrict__ stats,
                                                         float* __restrict__ part) {
  int c = blockIdx.x;
  int b = blockIdx.y;
  int d = threadIdx.x;
  const int rowsPer = TT / 16;
  int t0 = c * rowsPer;
  const float* xp = x + ((size_t)b*TT + t0) * DD + d;
  const float* st = stats + ((size_t)b*TT + t0) * 2;
  float s = 0.f;
  for (int t = 0; t < rowsPer; ++t)
    s += (xp[(size_t)t*DD] - st[2*t]) * st[2*t+1];
  part[((size_t)c*BB + b)*DD + d] = s;
}

__global__ __launch_bounds__(256) void mu_finalize_kernel(const float* __restrict__ part,
                                                          const float* __restrict__ gamma,
                                                          const float* __restrict__ beta,
                                                          float* __restrict__ mu) {
  int b = blockIdx.x;
  int d = threadIdx.x;
  float s = 0.f;
  #pragma unroll
  for (int c = 0; c < 16; ++c) s += part[((size_t)c*BB + b)*DD + d];
  mu[b*DD + d] = gamma[d] * s * (1.f/TT) + beta[d];
}

// ---- K3: cov via MFMA: C = Gram(Xc^T)/(T-1) + eps I, in-LDS transpose staging ----
__global__ __launch_bounds__(256) void cov_mfma(const float* __restrict__ x,
    const float* __restrict__ stats, const float* __restrict__ gamma,
    const float* __restrict__ beta, const float* __restrict__ mu,
    unsigned short* __restrict__ Ch, unsigned short* __restrict__ Cl,
    float* __restrict__ ssqp) {
  int tile = blockIdx.x;  // 0..9 upper-triangular tile pair
  int b = blockIdx.y;
  int p = 0, t = tile;
  while (t >= 4 - p) { t -= (4 - p); ++p; }
  int q = p + t;
  int i0 = p * 64, j0 = q * 64;
  bool diag = (p == q);

  __shared__ unsigned short sm[16384];       // sAh,sAl,sBh,sBl 8KB each = 32KB
  unsigned short* sAh = sm;
  unsigned short* sAl = sm + 4096;
  unsigned short* sBh = sm + 8192;
  unsigned short* sBl = sm + 12288;
  __shared__ float sGi[64], sBi[64], sGj[64], sBj[64];

  int tid = threadIdx.x;
  const float* mub = mu + (size_t)b*DD;
  if (tid < 64) {
    sGi[tid] = gamma[i0+tid]; sBi[tid] = beta[i0+tid] - mub[i0+tid];
    sGj[tid] = gamma[j0+tid]; sBj[tid] = beta[j0+tid] - mub[j0+tid];
  }
  __syncthreads();

  int wave = tid >> 6, lane = tid & 63;
  int lr = lane & 15, lg = lane >> 4;
  int tl = tid >> 2;           // t-local 0..63
  int d4 = (tid & 3) * 16;     // d-offset base (16 cols per thread)
  const float* xb  = x + (size_t)b*TT*DD;
  const float* stb = stats + (size_t)b*TT*2;

  f32x4 acc[4] = {};

  for (int k0 = 0; k0 < TT; k0 += 64) {
    int tg = k0 + tl;
    float mean = stb[2*tg], rstd = stb[2*tg+1];
    // i-stripe: transposed scatter writes sA[d][t] (bf16 hi/lo), swizzled
    {
      const float* xr = xb + (size_t)tg*DD + i0 + d4;
      #pragma unroll
      for (int qq = 0; qq < 4; ++qq) {
        float4 v = *(const float4*)&xr[qq*4];
        float vv[4] = {v.x, v.y, v.z, v.w};
        #pragma unroll
        for (int e2 = 0; e2 < 4; ++e2) {
          int d = d4 + qq*4 + e2;
          float xv = (vv[e2] - mean) * rstd * sGi[d] + sBi[d];
          unsigned short h = f2bf(xv), l = f2bf(xv - bf2f(h));
          int addr = d*64 + ((((tl>>3) ^ (d&7) ^ ((d>>3)&7)) & 7) << 3) + (tl & 7);
          sAh[addr] = h; sAl[addr] = l;
        }
      }
    }
    if (!diag) {
      const float* xr = xb + (size_t)tg*DD + j0 + d4;
      #pragma unroll
      for (int qq = 0; qq < 4; ++qq) {
        float4 v = *(const float4*)&xr[qq*4];
        float vv[4] = {v.x, v.y, v.z, v.w};
        #pragma unroll
        for (int e2 = 0; e2 < 4; ++e2) {
          int d = d4 + qq*4 + e2;
          float xv = (vv[e2] - mean) * rstd * sGj[d] + sBj[d];
          unsigned short h = f2bf(xv), l = f2bf(xv - bf2f(h));
          int addr = d*64 + ((((tl>>3) ^ (d&7) ^ ((d>>3)&7)) & 7) << 3) + (tl & 7);
          sBh[addr] = h; sBl[addr] = l;
        }
      }
    }
    __syncthreads();
    const unsigned short* pBh = diag ? sAh : sBh;
    const unsigned short* pBl = diag ? sAl : sBl;
    #pragma unroll
    for (int ks = 0; ks < 2; ++ks) {
      int rowA = wave*16 + lr;
      int cc = ks*4 + lg;
      int aoff = rowA*64 + (((cc ^ (rowA&7) ^ ((rowA>>3)&7)) & 7) << 3);
      bf16x8 ahi = *(const bf16x8*)&sAh[aoff];
      bf16x8 alo = *(const bf16x8*)&sAl[aoff];
      #pragma unroll
      for (int n = 0; n < 4; ++n) {
        int rowB = n*16 + lr;
        int boff = rowB*64 + (((cc ^ (rowB&7) ^ ((rowB>>3)&7)) & 7) << 3);
        bf16x8 bhi = *(const bf16x8*)&pBh[boff];
        bf16x8 blo = *(const bf16x8*)&pBl[boff];
        acc[n] = __builtin_amdgcn_mfma_f32_16x16x32_bf16(ahi, bhi, acc[n], 0, 0, 0);
        acc[n] = __builtin_amdgcn_mfma_f32_16x16x32_bf16(ahi, blo, acc[n], 0, 0, 0);
        acc[n] = __builtin_amdgcn_mfma_f32_16x16x32_bf16(alo, bhi, acc[n], 0, 0, 0);
      }
    }
    __syncthreads();
  }

  // epilogue: frags -> LDS f32 -> scale, split, store (+ mirror, + Frobenius^2)
  float* sC = (float*)sm;
  #pragma unroll
  for (int n = 0; n < 4; ++n)
    #pragma unroll
    for (int r = 0; r < 4; ++r)
      sC[(wave*16 + lg*4 + r)*65 + n*16 + lr] = acc[n][r];
  __syncthreads();
  unsigned short* Chb = Ch + (size_t)b*DD*DD;
  unsigned short* Clb = Cl + (size_t)b*DD*DD;
  const float invTm1 = 1.f / (float)(TT - 1);
  const float w = diag ? 1.f : 2.f;
  int row = tid >> 2, cb = (tid & 3) * 16;
  int gi = i0 + row;
  unsigned short hv[16], lv[16];
  float lssq = 0.f;
  #pragma unroll
  for (int e = 0; e < 16; ++e) {
    float v = sC[row*65 + cb + e] * invTm1;
    int gj = j0 + cb + e;
    if (gi == gj) v += WEPS;
    lssq += w * v * v;
    hv[e] = f2bf(v);
    lv[e] = f2bf(v - bf2f(hv[e]));
    if (!diag) { Chb[(size_t)gj*DD + gi] = hv[e]; Clb[(size_t)gj*DD + gi] = lv[e]; }
  }
  size_t go = (size_t)gi*DD + j0 + cb;
  *(bf16x8*)&Chb[go]     = *(bf16x8*)&hv[0];
  *(bf16x8*)&Chb[go + 8] = *(bf16x8*)&hv[8];
  *(bf16x8*)&Clb[go]     = *(bf16x8*)&lv[0];
  *(bf16x8*)&Clb[go + 8] = *(bf16x8*)&lv[8];
  #pragma unroll
  for (int off = 32; off; off >>= 1) lssq += __shfl_xor(lssq, off);
  __shared__ float red[4];
  if ((tid & 63) == 0) red[tid >> 6] = lssq;
  __syncthreads();
  if (tid == 0) ssqp[b*10 + tile] = red[0] + red[1] + red[2] + red[3];
}

// ---- K4: Y = C/||C||_F (re-split in place), Z = I ----
__global__ __launch_bounds__(256) void ns_init_kernel(unsigned short* __restrict__ Yh,
    unsigned short* __restrict__ Yl, unsigned short* __restrict__ Zh,
    unsigned short* __restrict__ Zl, const float* __restrict__ ssqp) {
  int b = blockIdx.y;
  int e = blockIdx.x * 256 + threadIdx.x;
  float ssq = 0.f;
  #pragma unroll
  for (int t = 0; t < 10; ++t) ssq += ssqp[b*10 + t];
  float invs = rsqrtf(ssq);
  size_t idx = (size_t)b*DD*DD + e;
  float y = (bf2f(Yh[idx]) + bf2f(Yl[idx])) * invs;
  unsigned short h = f2bf(y);
  Yh[idx] = h;
  Yl[idx] = f2bf(y - bf2f(h));
  bool dg = (e >> 8) == (e & 255);
  Zh[idx] = dg ? (unsigned short)0x3F80 : (unsigned short)0;
  Zl[idx] = 0;
}

// ---- K5: MFMA split-bf16 tile body: C = alpha*A*B + diagBeta*I (symmetric ops) ----
__device__ __forceinline__ void bgemm_tile(
    const unsigned short* __restrict__ Ah, const unsigned short* __restrict__ Al,
    const unsigned short* __restrict__ Bh, const unsigned short* __restrict__ Bl,
    unsigned short* __restrict__ Ch, unsigned short* __restrict__ Cl,
    float alpha, float diagBeta, int tilex, int b, unsigned short* sm) {
  unsigned short* sAh = sm;
  unsigned short* sAl = sm + 4096;
  unsigned short* sBh = sm + 8192;
  unsigned short* sBl = sm + 12288;

  const int tid = threadIdx.x;
  const int i0 = (tilex >> 2) * 64, j0 = (tilex & 3) * 64;
  const size_t mb = (size_t)b * DD * DD;
  const int wave = tid >> 6, lane = tid & 63;
  const int lr = lane & 15, lg = lane >> 4;
  const int r0 = tid >> 3;
  const int c0 = tid & 7;

  f32x4 acc[4] = {};

  for (int k0 = 0; k0 < DD; k0 += 64) {
    #pragma unroll
    for (int p = 0; p < 2; ++p) {
      int row = r0 + p * 32;
      int ld = row * 64 + ((c0 ^ (row & 7)) * 8);
      size_t ga = mb + (size_t)(i0 + row) * DD + k0 + c0 * 8;
      size_t gb = mb + (size_t)(j0 + row) * DD + k0 + c0 * 8;  // B symmetric
      *(bf16x8*)&sAh[ld] = *(const bf16x8*)&Ah[ga];
      *(bf16x8*)&sAl[ld] = *(const bf16x8*)&Al[ga];
      *(bf16x8*)&sBh[ld] = *(const bf16x8*)&Bh[gb];
      *(bf16x8*)&sBl[ld] = *(const bf16x8*)&Bl[gb];
    }
    __syncthreads();
    #pragma unroll
    for (int ks = 0; ks < 2; ++ks) {
      int rowA = wave * 16 + lr;
      int cc = ks * 4 + lg;
      int aoff = rowA * 64 + ((cc ^ (rowA & 7)) * 8);
      bf16x8 ahi = *(const bf16x8*)&sAh[aoff];
      bf16x8 alo = *(const bf16x8*)&sAl[aoff];
      #pragma unroll
      for (int n = 0; n < 4; ++n) {
        int rowB = n * 16 + lr;
        int boff = rowB * 64 + ((cc ^ (rowB & 7)) * 8);
        bf16x8 bhi = *(const bf16x8*)&sBh[boff];
        bf16x8 blo = *(const bf16x8*)&sBl[boff];
        acc[n] = __builtin_amdgcn_mfma_f32_16x16x32_bf16(ahi, bhi, acc[n], 0, 0, 0);
        acc[n] = __builtin_amdgcn_mfma_f32_16x16x32_bf16(ahi, blo, acc[n], 0, 0, 0);
        acc[n] = __builtin_amdgcn_mfma_f32_16x16x32_bf16(alo, bhi, acc[n], 0, 0, 0);
      }
    }
    __syncthreads();
  }

  float* sC = (float*)sm;
  #pragma unroll
  for (int n = 0; n < 4; ++n)
    #pragma unroll
    for (int r = 0; r < 4; ++r)
      sC[(wave * 16 + lg * 4 + r) * 65 + n * 16 + lr] = acc[n][r];
  __syncthreads();
  int row = tid >> 2, cb = (tid & 3) * 16;
  unsigned short hv[16], lv[16];
  #pragma unroll
  for (int e = 0; e < 16; ++e) {
    float v = alpha * sC[row * 65 + cb + e];
    if (i0 + row == j0 + cb + e) v += diagBeta;
    hv[e] = f2bf(v);
    lv[e] = f2bf(v - bf2f(hv[e]));
  }
  size_t go = mb + (size_t)(i0 + row) * DD + j0 + cb;
  unsigned short* Chp = Ch; unsigned short* Clp = Cl;
  *(bf16x8*)&Chp[go]     = *(bf16x8*)&hv[0];
  *(bf16x8*)&Chp[go + 8] = *(bf16x8*)&hv[8];
  *(bf16x8*)&Clp[go]     = *(bf16x8*)&lv[0];
  *(bf16x8*)&Clp[go + 8] = *(bf16x8*)&lv[8];
}

__global__ __launch_bounds__(256) void bgemm_mfma(
    const unsigned short* __restrict__ Ah, const unsigned short* __restrict__ Al,
    const unsigned short* __restrict__ Bh, const unsigned short* __restrict__ Bl,
    unsigned short* __restrict__ Ch, unsigned short* __restrict__ Cl,
    float alpha, float diagBeta) {
  __shared__ unsigned short sm[16384];
  bgemm_tile(Ah, Al, Bh, Bl, Ch, Cl, alpha, diagBeta, blockIdx.x, blockIdx.y, sm);
}

// fused dual GEMM: half0: C0 = 0.5*A0*B0 ; half1: C1 = 0.5*A1*B1
__global__ __launch_bounds__(256) void bgemm_dual(
    const unsigned short* __restrict__ A0h, const unsigned short* __restrict__ A0l,
    const unsigned short* __restrict__ B0h, const unsigned short* __restrict__ B0l,
    unsigned short* __restrict__ C0h, unsigned short* __restrict__ C0l,
    const unsigned short* __restrict__ A1h, const unsigned short* __restrict__ A1l,
    const unsigned short* __restrict__ B1h, const unsigned short* __restrict__ B1l,
    unsigned short* __restrict__ C1h, unsigned short* __restrict__ C1l) {
  __shared__ unsigned short sm[16384];
  int half = blockIdx.x >> 4, tile = blockIdx.x & 15;
  if (half == 0)
    bgemm_tile(A0h, A0l, B0h, B0l, C0h, C0l, 0.5f, 0.f, tile, blockIdx.y, sm);
  else
    bgemm_tile(A1h, A1l, B1h, B1l, C1h, C1l, 0.5f, 0.f, tile, blockIdx.y, sm);
}

// ---- K6: out = Xc @ (Z * ssq^{-1/4}) via MFMA (Z symmetric -> row-fed B) ----
__global__ __launch_bounds__(256) void out_mfma(const float* __restrict__ x,
    const float* __restrict__ stats, const float* __restrict__ gamma,
    const float* __restrict__ beta, const float* __restrict__ mu,
    const unsigned short* __restrict__ Zh, const unsigned short* __restrict__ Zl,
    const float* __restrict__ ssqp, float* __restrict__ out) {
  int b = blockIdx.y;
  int t0 = (blockIdx.x >> 2) * 64, f0 = (blockIdx.x & 3) * 64;
  __shared__ unsigned short sm[16384];
  unsigned short* sAh = sm;
  unsigned short* sAl = sm + 4096;
  unsigned short* sBh = sm + 8192;
  unsigned short* sBl = sm + 12288;
  __shared__ float sG[256], sBs[256];

  int tid = threadIdx.x;
  sG[tid] = gamma[tid];
  sBs[tid] = beta[tid] - mu[(size_t)b*DD + tid];
  __syncthreads();

  const int wave = tid >> 6, lane = tid & 63;
  const int lr = lane & 15, lg = lane >> 4;
  const int r0 = tid >> 3, c0 = tid & 7;
  const float* xb  = x + (size_t)b*TT*DD;
  const float* stb = stats + (size_t)b*TT*2;
  const unsigned short* Zhb = Zh + (size_t)b*DD*DD;
  const unsigned short* Zlb = Zl + (size_t)b*DD*DD;

  f32x4 acc[4] = {};

  for (int k0 = 0; k0 < DD; k0 += 64) {
    #pragma unroll
    for (int p = 0; p < 2; ++p) {
      int row = r0 + p * 32;
      int trow = t0 + row;
      float mean = stb[2*trow], rstd = stb[2*trow+1];
      const float* xr = xb + (size_t)trow*DD + k0 + c0*8;
      unsigned short h8[8], l8[8];
      #pragma unroll
      for (int qq = 0; qq < 2; ++qq) {
        float4 v = *(const float4*)&xr[qq*4];
        float vv[4] = {v.x, v.y, v.z, v.w};
        #pragma unroll
        for (int e2 = 0; e2 < 4; ++e2) {
          int d = k0 + c0*8 + qq*4 + e2;
          float xv = (vv[e2] - mean) * rstd * sG[d] + sBs[d];
          h8[qq*4+e2] = f2bf(xv);
          l8[qq*4+e2] = f2bf(xv - bf2f(h8[qq*4+e2]));
        }
      }
      int ld = row * 64 + ((c0 ^ (row & 7)) * 8);
      *(bf16x8*)&sAh[ld] = *(bf16x8*)&h8[0];
      *(bf16x8*)&sAl[ld] = *(bf16x8*)&l8[0];
      size_t gz = (size_t)(f0 + row) * DD + k0 + c0 * 8;
      *(bf16x8*)&sBh[ld] = *(const bf16x8*)&Zhb[gz];
      *(bf16x8*)&sBl[ld] = *(const bf16x8*)&Zlb[gz];
    }
    __syncthreads();
    #pragma unroll
    for (int ks = 0; ks < 2; ++ks) {
      int rowA = wave * 16 + lr;
      int cc = ks * 4 + lg;
      int aoff = rowA * 64 + ((cc ^ (rowA & 7)) * 8);
      bf16x8 ahi = *(const bf16x8*)&sAh[aoff];
      bf16x8 alo = *(const bf16x8*)&sAl[aoff];
      #pragma unroll
      for (int n = 0; n < 4; ++n) {
        int rowB = n * 16 + lr;
        int boff = rowB * 64 + ((cc ^ (rowB & 7)) * 8);
        bf16x8 bhi = *(const bf16x8*)&sBh[boff];
        bf16x8 blo = *(const bf16x8*)&sBl[boff];
        acc[n] = __builtin_amdgcn_mfma_f32_16x16x32_bf16(ahi, bhi, acc[n], 0, 0, 0);
        acc[n] = __builtin_amdgcn_mfma_f32_16x16x32_bf16(ahi, blo, acc[n], 0, 0, 0);
        acc[n] = __builtin_amdgcn_mfma_f32_16x16x32_bf16(alo, bhi, acc[n], 0, 0, 0);
      }
    }
    __syncthreads();
  }

  float ssq = 0.f;
  #pragma unroll
  for (int t = 0; t < 10; ++t) ssq += ssqp[b*10 + t];
  float rs = rsqrtf(sqrtf(ssq));   // ssq^{-1/4} = ||C||_F^{-1/2}
  float* ob = out + (size_t)b*TT*DD;
  #pragma unroll
  for (int n = 0; n < 4; ++n)
    #pragma unroll
    for (int r = 0; r < 4; ++r)
      ob[(size_t)(t0 + wave*16 + lg*4 + r)*DD + f0 + n*16 + lr] = acc[n][r] * rs;
}

extern "C" void kernel_launch(void* const* d_in, const int* in_sizes, int n_in,
                              void* d_out, int out_size, void* d_ws, size_t ws_size,
                              hipStream_t stream) {
  const float* x     = (const float*)d_in[0];
  const float* gamma = (const float*)d_in[1];
  const float* beta  = (const float*)d_in[2];
  float* out = (float*)d_out;

  float* wsf   = (float*)d_ws;
  float* stats = wsf;                  // 262144 floats
  float* part  = wsf + 262144;         // 262144
  float* mu    = wsf + 524288;         // 16384
  float* ssqp  = wsf + 540672;         // 4096 (pad)
  unsigned short* nsb = (unsigned short*)(wsf + 544768);
  const size_t MATU = (size_t)BB * DD * DD;      // 4194304 ushorts per plane
  unsigned short *H[5], *L[5];
  for (int k = 0; k < 5; ++k) { H[k] = nsb + (size_t)k * 2 * MATU; L[k] = H[k] + MATU; }

  ln_stats_kernel<<<BB*TT/4, 256, 0, stream>>>(x, stats);
  mu_partial_kernel<<<dim3(16, BB), 256, 0, stream>>>(x, stats, part);
  mu_finalize_kernel<<<BB, 256, 0, stream>>>(part, gamma, beta, mu);
  cov_mfma<<<dim3(10, BB), 256, 0, stream>>>(x, stats, gamma, beta, mu, H[0], L[0], ssqp);
  ns_init_kernel<<<dim3(256, BB), 256, 0, stream>>>(H[0], L[0], H[1], L[1], ssqp);

  // Coupled NS, 5-buffer rotation; Y',Z' fused per iteration.
  int y = 0, z = 1, m = 2, s = 3, u = 4;
  for (int it = 0; it < NS_ITERS - 1; ++it) {
    bgemm_mfma<<<dim3(16, BB), 256, 0, stream>>>(H[z], L[z], H[y], L[y], H[m], L[m], -1.f, 3.f);
    bgemm_dual<<<dim3(32, BB), 256, 0, stream>>>(H[y], L[y], H[m], L[m], H[s], L[s],
                                                 H[m], L[m], H[z], L[z], H[u], L[u]);
    int oy = y, oz = z;
    y = s; z = u; s = oy; u = oz;
  }
  // final iteration: only Z' needed
  bgemm_mfma<<<dim3(16, BB), 256, 0, stream>>>(H[z], L[z], H[y], L[y], H[m], L[m], -1.f, 3.f);
  bgemm_mfma<<<dim3(16, BB), 256, 0, stream>>>(H[m], L[m], H[z], L[z], H[s], L[s], 0.5f, 0.f);
  z = s;

  out_mfma<<<dim3(128, BB), 256, 0, stream>>>(x, stats, gamma, beta, mu, H[z], L[z], ssqp, out);
}

// Round 5
// 692.536 us; speedup vs baseline: 4.1279x; 1.2079x over previous
//
#include <hip/hip_runtime.h>
#include <cstddef>

#define TT 2048
#define BB 64
#define DD 256
#define LN_EPS 1e-5f
#define WEPS 1e-4f
#define NS_ITERS 7

typedef __attribute__((ext_vector_type(8))) short bf16x8;
typedef __attribute__((ext_vector_type(4))) float f32x4;

__device__ __forceinline__ unsigned short f2bf(float f) {
  unsigned u = __float_as_uint(f);
  return (unsigned short)((u + 0x7FFFu + ((u >> 16) & 1u)) >> 16);
}
__device__ __forceinline__ float bf2f(unsigned short h) {
  return __uint_as_float(((unsigned)h) << 16);
}

// ---- K1: per-row LN stats (mean, rstd) ----
__global__ __launch_bounds__(256) void ln_stats_kernel(const float* __restrict__ x,
                                                       float* __restrict__ stats) {
  int row  = blockIdx.x * 4 + (threadIdx.x >> 6);
  int lane = threadIdx.x & 63;
  const float4* xr = reinterpret_cast<const float4*>(x + (size_t)row * DD);
  float4 v = xr[lane];
  float s  = v.x + v.y + v.z + v.w;
  float sq = v.x*v.x + v.y*v.y + v.z*v.z + v.w*v.w;
  #pragma unroll
  for (int off = 32; off; off >>= 1) { s += __shfl_xor(s, off); sq += __shfl_xor(sq, off); }
  if (lane == 0) {
    float mean = s * (1.f/DD);
    float var  = fmaxf(sq * (1.f/DD) - mean*mean, 0.f);
    stats[2*row]   = mean;
    stats[2*row+1] = rsqrtf(var + LN_EPS);
  }
}

// ---- K2a/K2b: column means of LN(x) per batch ----
__global__ __launch_bounds__(256) void mu_partial_kernel(const float* __restrict__ x,
                                                         const float* __restrict__ stats,
                                                         float* __restrict__ part) {
  int c = blockIdx.x;
  int b = blockIdx.y;
  int d = threadIdx.x;
  const int rowsPer = TT / 16;
  int t0 = c * rowsPer;
  const float* xp = x + ((size_t)b*TT + t0) * DD + d;
  const float* st = stats + ((size_t)b*TT + t0) * 2;
  float s = 0.f;
  for (int t = 0; t < rowsPer; ++t)
    s += (xp[(size_t)t*DD] - st[2*t]) * st[2*t+1];
  part[((size_t)c*BB + b)*DD + d] = s;
}

__global__ __launch_bounds__(256) void mu_finalize_kernel(const float* __restrict__ part,
                                                          const float* __restrict__ gamma,
                                                          const float* __restrict__ beta,
                                                          float* __restrict__ mu) {
  int b = blockIdx.x;
  int d = threadIdx.x;
  float s = 0.f;
  #pragma unroll
  for (int c = 0; c < 16; ++c) s += part[((size_t)c*BB + b)*DD + d];
  mu[b*DD + d] = gamma[d] * s * (1.f/TT) + beta[d];
}

// ---- K3: cov via MFMA: C = Gram(Xc^T)/(T-1) + eps I, in-LDS transpose staging ----
__global__ __launch_bounds__(256) void cov_mfma(const float* __restrict__ x,
    const float* __restrict__ stats, const float* __restrict__ gamma,
    const float* __restrict__ beta, const float* __restrict__ mu,
    unsigned short* __restrict__ Ch, unsigned short* __restrict__ Cl,
    float* __restrict__ ssqp) {
  int tile = blockIdx.x;  // 0..9 upper-triangular tile pair
  int b = blockIdx.y;
  int p = 0, t = tile;
  while (t >= 4 - p) { t -= (4 - p); ++p; }
  int q = p + t;
  int i0 = p * 64, j0 = q * 64;
  bool diag = (p == q);

  __shared__ unsigned short sm[16384];       // sAh,sAl,sBh,sBl 8KB each = 32KB
  unsigned short* sAh = sm;
  unsigned short* sAl = sm + 4096;
  unsigned short* sBh = sm + 8192;
  unsigned short* sBl = sm + 12288;
  __shared__ float sGi[64], sBi[64], sGj[64], sBj[64];

  int tid = threadIdx.x;
  const float* mub = mu + (size_t)b*DD;
  if (tid < 64) {
    sGi[tid] = gamma[i0+tid]; sBi[tid] = beta[i0+tid] - mub[i0+tid];
    sGj[tid] = gamma[j0+tid]; sBj[tid] = beta[j0+tid] - mub[j0+tid];
  }
  __syncthreads();

  int wave = tid >> 6, lane = tid & 63;
  int lr = lane & 15, lg = lane >> 4;
  int tl = tid >> 2;           // t-local 0..63
  int d4 = (tid & 3) * 16;     // d-offset base (16 cols per thread)
  const float* xb  = x + (size_t)b*TT*DD;
  const float* stb = stats + (size_t)b*TT*2;

  f32x4 acc[4] = {};

  for (int k0 = 0; k0 < TT; k0 += 64) {
    int tg = k0 + tl;
    float mean = stb[2*tg], rstd = stb[2*tg+1];
    {
      const float* xr = xb + (size_t)tg*DD + i0 + d4;
      #pragma unroll
      for (int qq = 0; qq < 4; ++qq) {
        float4 v = *(const float4*)&xr[qq*4];
        float vv[4] = {v.x, v.y, v.z, v.w};
        #pragma unroll
        for (int e2 = 0; e2 < 4; ++e2) {
          int d = d4 + qq*4 + e2;
          float xv = (vv[e2] - mean) * rstd * sGi[d] + sBi[d];
          unsigned short h = f2bf(xv), l = f2bf(xv - bf2f(h));
          int addr = d*64 + ((((tl>>3) ^ (d&7) ^ ((d>>3)&7)) & 7) << 3) + (tl & 7);
          sAh[addr] = h; sAl[addr] = l;
        }
      }
    }
    if (!diag) {
      const float* xr = xb + (size_t)tg*DD + j0 + d4;
      #pragma unroll
      for (int qq = 0; qq < 4; ++qq) {
        float4 v = *(const float4*)&xr[qq*4];
        float vv[4] = {v.x, v.y, v.z, v.w};
        #pragma unroll
        for (int e2 = 0; e2 < 4; ++e2) {
          int d = d4 + qq*4 + e2;
          float xv = (vv[e2] - mean) * rstd * sGj[d] + sBj[d];
          unsigned short h = f2bf(xv), l = f2bf(xv - bf2f(h));
          int addr = d*64 + ((((tl>>3) ^ (d&7) ^ ((d>>3)&7)) & 7) << 3) + (tl & 7);
          sBh[addr] = h; sBl[addr] = l;
        }
      }
    }
    __syncthreads();
    const unsigned short* pBh = diag ? sAh : sBh;
    const unsigned short* pBl = diag ? sAl : sBl;
    #pragma unroll
    for (int ks = 0; ks < 2; ++ks) {
      int rowA = wave*16 + lr;
      int cc = ks*4 + lg;
      int aoff = rowA*64 + (((cc ^ (rowA&7) ^ ((rowA>>3)&7)) & 7) << 3);
      bf16x8 ahi = *(const bf16x8*)&sAh[aoff];
      bf16x8 alo = *(const bf16x8*)&sAl[aoff];
      #pragma unroll
      for (int n = 0; n < 4; ++n) {
        int rowB = n*16 + lr;
        int boff = rowB*64 + (((cc ^ (rowB&7) ^ ((rowB>>3)&7)) & 7) << 3);
        bf16x8 bhi = *(const bf16x8*)&pBh[boff];
        bf16x8 blo = *(const bf16x8*)&pBl[boff];
        acc[n] = __builtin_amdgcn_mfma_f32_16x16x32_bf16(ahi, bhi, acc[n], 0, 0, 0);
        acc[n] = __builtin_amdgcn_mfma_f32_16x16x32_bf16(ahi, blo, acc[n], 0, 0, 0);
        acc[n] = __builtin_amdgcn_mfma_f32_16x16x32_bf16(alo, bhi, acc[n], 0, 0, 0);
      }
    }
    __syncthreads();
  }

  float* sC = (float*)sm;
  #pragma unroll
  for (int n = 0; n < 4; ++n)
    #pragma unroll
    for (int r = 0; r < 4; ++r)
      sC[(wave*16 + lg*4 + r)*65 + n*16 + lr] = acc[n][r];
  __syncthreads();
  unsigned short* Chb = Ch + (size_t)b*DD*DD;
  unsigned short* Clb = Cl + (size_t)b*DD*DD;
  const float invTm1 = 1.f / (float)(TT - 1);
  const float w = diag ? 1.f : 2.f;
  int row = tid >> 2, cb = (tid & 3) * 16;
  int gi = i0 + row;
  unsigned short hv[16], lv[16];
  float lssq = 0.f;
  #pragma unroll
  for (int e = 0; e < 16; ++e) {
    float v = sC[row*65 + cb + e] * invTm1;
    int gj = j0 + cb + e;
    if (gi == gj) v += WEPS;
    lssq += w * v * v;
    hv[e] = f2bf(v);
    lv[e] = f2bf(v - bf2f(hv[e]));
    if (!diag) { Chb[(size_t)gj*DD + gi] = hv[e]; Clb[(size_t)gj*DD + gi] = lv[e]; }
  }
  size_t go = (size_t)gi*DD + j0 + cb;
  *(bf16x8*)&Chb[go]     = *(bf16x8*)&hv[0];
  *(bf16x8*)&Chb[go + 8] = *(bf16x8*)&hv[8];
  *(bf16x8*)&Clb[go]     = *(bf16x8*)&lv[0];
  *(bf16x8*)&Clb[go + 8] = *(bf16x8*)&lv[8];
  #pragma unroll
  for (int off = 32; off; off >>= 1) lssq += __shfl_xor(lssq, off);
  __shared__ float red[4];
  if ((tid & 63) == 0) red[tid >> 6] = lssq;
  __syncthreads();
  if (tid == 0) ssqp[b*10 + tile] = red[0] + red[1] + red[2] + red[3];
}

// ---- K3b: power iteration for lambda_max; s = 1.12 * ||C v||, v unit ----
__global__ __launch_bounds__(256) void power_kernel(
    const unsigned short* __restrict__ Ch, const unsigned short* __restrict__ Cl,
    float* __restrict__ sbuf) {
  int b = blockIdx.x, tid = threadIdx.x;
  __shared__ float v[DD];
  __shared__ float red[4];
  v[tid] = 1.f;
  __syncthreads();
  const unsigned short* rh = Ch + (size_t)b*DD*DD + (size_t)tid*DD;
  const unsigned short* rl = Cl + (size_t)b*DD*DD + (size_t)tid*DD;
  float lam = 1.f;
  for (int it = 0; it < 10; ++it) {
    float w = 0.f;
    #pragma unroll 4
    for (int j8 = 0; j8 < 32; ++j8) {
      bf16x8 hq = *(const bf16x8*)&rh[j8*8];
      bf16x8 lq = *(const bf16x8*)&rl[j8*8];
      #pragma unroll
      for (int e = 0; e < 8; ++e)
        w += (bf2f((unsigned short)hq[e]) + bf2f((unsigned short)lq[e])) * v[j8*8+e];
    }
    float ssq = w * w;
    #pragma unroll
    for (int off = 32; off; off >>= 1) ssq += __shfl_xor(ssq, off);
    if ((tid & 63) == 0) red[tid >> 6] = ssq;
    __syncthreads();
    float nrm = sqrtf(red[0] + red[1] + red[2] + red[3]);
    lam = nrm;
    v[tid] = w / nrm;
    __syncthreads();
  }
  if (tid == 0) sbuf[b] = lam * 1.12f;
}

// ---- K4: Y = C/s (re-split in place), Z = I ----
__global__ __launch_bounds__(256) void ns_init_kernel(unsigned short* __restrict__ Yh,
    unsigned short* __restrict__ Yl, unsigned short* __restrict__ Zh,
    unsigned short* __restrict__ Zl, const float* __restrict__ sbuf) {
  int b = blockIdx.y;
  int e = blockIdx.x * 256 + threadIdx.x;
  float invs = 1.f / sbuf[b];
  size_t idx = (size_t)b*DD*DD + e;
  float y = (bf2f(Yh[idx]) + bf2f(Yl[idx])) * invs;
  unsigned short h = f2bf(y);
  Yh[idx] = h;
  Yl[idx] = f2bf(y - bf2f(h));
  bool dg = (e >> 8) == (e & 255);
  Zh[idx] = dg ? (unsigned short)0x3F80 : (unsigned short)0;
  Zl[idx] = 0;
}

// ---- K5: 128x128-tile MFMA split-bf16 GEMM body (symmetric operands) ----
// 512 threads = 8 waves (2x4), each wave 64x32 of the 128x128 tile.
__device__ __forceinline__ void bgemm_tile2(
    const unsigned short* __restrict__ Ah, const unsigned short* __restrict__ Al,
    const unsigned short* __restrict__ Bh, const unsigned short* __restrict__ Bl,
    unsigned short* __restrict__ Ch, unsigned short* __restrict__ Cl,
    float alpha, float diagBeta, int tilex, int b, unsigned short* sm) {
  unsigned short* sAh = sm;
  unsigned short* sAl = sm + 8192;
  unsigned short* sBh = sm + 16384;
  unsigned short* sBl = sm + 24576;

  const int tid = threadIdx.x;
  const int i0g = (tilex >> 1) * 128, j0g = (tilex & 1) * 128;
  const size_t mb = (size_t)b * DD * DD;
  const int wave = tid >> 6, lane = tid & 63;
  const int wr = wave >> 2, wc = wave & 3;
  const int lr = lane & 15, lg = lane >> 4;
  const int r0 = tid >> 3;   // 0..63
  const int c0 = tid & 7;

  f32x4 acc[8] = {};

  for (int k0 = 0; k0 < DD; k0 += 64) {
    #pragma unroll
    for (int p = 0; p < 2; ++p) {
      int row = r0 + p * 64;
      int ld = row * 64 + ((c0 ^ (row & 7)) * 8);
      size_t ga = mb + (size_t)(i0g + row) * DD + k0 + c0 * 8;
      size_t gb = mb + (size_t)(j0g + row) * DD + k0 + c0 * 8;  // B symmetric
      *(bf16x8*)&sAh[ld] = *(const bf16x8*)&Ah[ga];
      *(bf16x8*)&sAl[ld] = *(const bf16x8*)&Al[ga];
      *(bf16x8*)&sBh[ld] = *(const bf16x8*)&Bh[gb];
      *(bf16x8*)&sBl[ld] = *(const bf16x8*)&Bl[gb];
    }
    __syncthreads();
    #pragma unroll
    for (int ks = 0; ks < 2; ++ks) {
      int cc = ks * 4 + lg;
      bf16x8 bh[2], bl[2];
      #pragma unroll
      for (int n = 0; n < 2; ++n) {
        int rowB = wc * 32 + n * 16 + lr;
        int boff = rowB * 64 + ((cc ^ (rowB & 7)) * 8);
        bh[n] = *(const bf16x8*)&sBh[boff];
        bl[n] = *(const bf16x8*)&sBl[boff];
      }
      #pragma unroll
      for (int m = 0; m < 4; ++m) {
        int rowA = wr * 64 + m * 16 + lr;
        int aoff = rowA * 64 + ((cc ^ (rowA & 7)) * 8);
        bf16x8 ah = *(const bf16x8*)&sAh[aoff];
        bf16x8 al = *(const bf16x8*)&sAl[aoff];
        #pragma unroll
        for (int n = 0; n < 2; ++n) {
          acc[m*2+n] = __builtin_amdgcn_mfma_f32_16x16x32_bf16(ah, bh[n], acc[m*2+n], 0, 0, 0);
          acc[m*2+n] = __builtin_amdgcn_mfma_f32_16x16x32_bf16(ah, bl[n], acc[m*2+n], 0, 0, 0);
          acc[m*2+n] = __builtin_amdgcn_mfma_f32_16x16x32_bf16(al, bh[n], acc[m*2+n], 0, 0, 0);
        }
      }
    }
    __syncthreads();
  }

  // direct split stores
  #pragma unroll
  for (int m = 0; m < 4; ++m) {
    #pragma unroll
    for (int n = 0; n < 2; ++n) {
      int col = j0g + wc * 32 + n * 16 + lr;
      int row0 = i0g + wr * 64 + m * 16 + lg * 4;
      #pragma unroll
      for (int r = 0; r < 4; ++r) {
        float vv = alpha * acc[m*2+n][r];
        int row = row0 + r;
        if (row == col) vv += diagBeta;
        unsigned short h = f2bf(vv), l = f2bf(vv - bf2f(h));
        Ch[mb + (size_t)row * DD + col] = h;
        Cl[mb + (size_t)row * DD + col] = l;
      }
    }
  }
}

__global__ __launch_bounds__(512) void bgemm_mfma2(
    const unsigned short* __restrict__ Ah, const unsigned short* __restrict__ Al,
    const unsigned short* __restrict__ Bh, const unsigned short* __restrict__ Bl,
    unsigned short* __restrict__ Ch, unsigned short* __restrict__ Cl,
    float alpha, float diagBeta) {
  __shared__ unsigned short sm[32768];
  bgemm_tile2(Ah, Al, Bh, Bl, Ch, Cl, alpha, diagBeta, blockIdx.x, blockIdx.y, sm);
}

__global__ __launch_bounds__(512) void bgemm_dual2(
    const unsigned short* __restrict__ A0h, const unsigned short* __restrict__ A0l,
    const unsigned short* __restrict__ B0h, const unsigned short* __restrict__ B0l,
    unsigned short* __restrict__ C0h, unsigned short* __restrict__ C0l,
    const unsigned short* __restrict__ A1h, const unsigned short* __restrict__ A1l,
    const unsigned short* __restrict__ B1h, const unsigned short* __restrict__ B1l,
    unsigned short* __restrict__ C1h, unsigned short* __restrict__ C1l) {
  __shared__ unsigned short sm[32768];
  int half = blockIdx.x >> 2, tile = blockIdx.x & 3;
  if (half == 0)
    bgemm_tile2(A0h, A0l, B0h, B0l, C0h, C0l, 0.5f, 0.f, tile, blockIdx.y, sm);
  else
    bgemm_tile2(A1h, A1l, B1h, B1l, C1h, C1l, 0.5f, 0.f, tile, blockIdx.y, sm);
}

// ---- K6: out = Xc @ (Z / sqrt(s)) via MFMA (Z symmetric -> row-fed B) ----
__global__ __launch_bounds__(256) void out_mfma(const float* __restrict__ x,
    const float* __restrict__ stats, const float* __restrict__ gamma,
    const float* __restrict__ beta, const float* __restrict__ mu,
    const unsigned short* __restrict__ Zh, const unsigned short* __restrict__ Zl,
    const float* __restrict__ sbuf, float* __restrict__ out) {
  int b = blockIdx.y;
  int t0 = (blockIdx.x >> 2) * 64, f0 = (blockIdx.x & 3) * 64;
  __shared__ unsigned short sm[16384];
  unsigned short* sAh = sm;
  unsigned short* sAl = sm + 4096;
  unsigned short* sBh = sm + 8192;
  unsigned short* sBl = sm + 12288;
  __shared__ float sG[256], sBs[256];

  int tid = threadIdx.x;
  sG[tid] = gamma[tid];
  sBs[tid] = beta[tid] - mu[(size_t)b*DD + tid];
  __syncthreads();

  const int wave = tid >> 6, lane = tid & 63;
  const int lr = lane & 15, lg = lane >> 4;
  const int r0 = tid >> 3, c0 = tid & 7;
  const float* xb  = x + (size_t)b*TT*DD;
  const float* stb = stats + (size_t)b*TT*2;
  const unsigned short* Zhb = Zh + (size_t)b*DD*DD;
  const unsigned short* Zlb = Zl + (size_t)b*DD*DD;

  f32x4 acc[4] = {};

  for (int k0 = 0; k0 < DD; k0 += 64) {
    #pragma unroll
    for (int p = 0; p < 2; ++p) {
      int row = r0 + p * 32;
      int trow = t0 + row;
      float mean = stb[2*trow], rstd = stb[2*trow+1];
      const float* xr = xb + (size_t)trow*DD + k0 + c0*8;
      unsigned short h8[8], l8[8];
      #pragma unroll
      for (int qq = 0; qq < 2; ++qq) {
        float4 v = *(const float4*)&xr[qq*4];
        float vv[4] = {v.x, v.y, v.z, v.w};
        #pragma unroll
        for (int e2 = 0; e2 < 4; ++e2) {
          int d = k0 + c0*8 + qq*4 + e2;
          float xv = (vv[e2] - mean) * rstd * sG[d] + sBs[d];
          h8[qq*4+e2] = f2bf(xv);
          l8[qq*4+e2] = f2bf(xv - bf2f(h8[qq*4+e2]));
        }
      }
      int ld = row * 64 + ((c0 ^ (row & 7)) * 8);
      *(bf16x8*)&sAh[ld] = *(bf16x8*)&h8[0];
      *(bf16x8*)&sAl[ld] = *(bf16x8*)&l8[0];
      size_t gz = (size_t)(f0 + row) * DD + k0 + c0 * 8;
      *(bf16x8*)&sBh[ld] = *(const bf16x8*)&Zhb[gz];
      *(bf16x8*)&sBl[ld] = *(const bf16x8*)&Zlb[gz];
    }
    __syncthreads();
    #pragma unroll
    for (int ks = 0; ks < 2; ++ks) {
      int rowA = wave * 16 + lr;
      int cc = ks * 4 + lg;
      int aoff = rowA * 64 + ((cc ^ (rowA & 7)) * 8);
      bf16x8 ahi = *(const bf16x8*)&sAh[aoff];
      bf16x8 alo = *(const bf16x8*)&sAl[aoff];
      #pragma unroll
      for (int n = 0; n < 4; ++n) {
        int rowB = n * 16 + lr;
        int boff = rowB * 64 + ((cc ^ (rowB & 7)) * 8);
        bf16x8 bhi = *(const bf16x8*)&sBh[boff];
        bf16x8 blo = *(const bf16x8*)&sBl[boff];
        acc[n] = __builtin_amdgcn_mfma_f32_16x16x32_bf16(ahi, bhi, acc[n], 0, 0, 0);
        acc[n] = __builtin_amdgcn_mfma_f32_16x16x32_bf16(ahi, blo, acc[n], 0, 0, 0);
        acc[n] = __builtin_amdgcn_mfma_f32_16x16x32_bf16(alo, bhi, acc[n], 0, 0, 0);
      }
    }
    __syncthreads();
  }

  float rs = rsqrtf(sbuf[b]);
  float* ob = out + (size_t)b*TT*DD;
  #pragma unroll
  for (int n = 0; n < 4; ++n)
    #pragma unroll
    for (int r = 0; r < 4; ++r)
      ob[(size_t)(t0 + wave*16 + lg*4 + r)*DD + f0 + n*16 + lr] = acc[n][r] * rs;
}

extern "C" void kernel_launch(void* const* d_in, const int* in_sizes, int n_in,
                              void* d_out, int out_size, void* d_ws, size_t ws_size,
                              hipStream_t stream) {
  const float* x     = (const float*)d_in[0];
  const float* gamma = (const float*)d_in[1];
  const float* beta  = (const float*)d_in[2];
  float* out = (float*)d_out;

  float* wsf   = (float*)d_ws;
  float* stats = wsf;                  // 262144 floats
  float* part  = wsf + 262144;         // 262144
  float* mu    = wsf + 524288;         // 16384
  float* ssqp  = wsf + 540672;         // 640 (+pad)
  float* sbuf  = wsf + 541696;         // 64
  unsigned short* nsb = (unsigned short*)(wsf + 544768);
  const size_t MATU = (size_t)BB * DD * DD;      // 4194304 ushorts per plane
  unsigned short *H[5], *L[5];
  for (int k = 0; k < 5; ++k) { H[k] = nsb + (size_t)k * 2 * MATU; L[k] = H[k] + MATU; }

  ln_stats_kernel<<<BB*TT/4, 256, 0, stream>>>(x, stats);
  mu_partial_kernel<<<dim3(16, BB), 256, 0, stream>>>(x, stats, part);
  mu_finalize_kernel<<<BB, 256, 0, stream>>>(part, gamma, beta, mu);
  cov_mfma<<<dim3(10, BB), 256, 0, stream>>>(x, stats, gamma, beta, mu, H[0], L[0], ssqp);
  power_kernel<<<BB, 256, 0, stream>>>(H[0], L[0], sbuf);
  ns_init_kernel<<<dim3(256, BB), 256, 0, stream>>>(H[0], L[0], H[1], L[1], sbuf);

  // Coupled NS, 5-buffer rotation; Y',Z' fused per iteration.
  int y = 0, z = 1, m = 2, s = 3, u = 4;
  for (int it = 0; it < NS_ITERS - 1; ++it) {
    bgemm_mfma2<<<dim3(4, BB), 512, 0, stream>>>(H[z], L[z], H[y], L[y], H[m], L[m], -1.f, 3.f);
    bgemm_dual2<<<dim3(8, BB), 512, 0, stream>>>(H[y], L[y], H[m], L[m], H[s], L[s],
                                                 H[m], L[m], H[z], L[z], H[u], L[u]);
    int oy = y, oz = z;
    y = s; z = u; s = oy; u = oz;
  }
  // final iteration: only Z' needed
  bgemm_mfma2<<<dim3(4, BB), 512, 0, stream>>>(H[z], L[z], H[y], L[y], H[m], L[m], -1.f, 3.f);
  bgemm_mfma2<<<dim3(4, BB), 512, 0, stream>>>(H[m], L[m], H[z], L[z], H[s], L[s], 0.5f, 0.f);
  z = s;

  out_mfma<<<dim3(128, BB), 256, 0, stream>>>(x, stats, gamma, beta, mu, H[z], L[z], sbuf, out);
}

// Round 6
// 462.505 us; speedup vs baseline: 6.1810x; 1.4974x over previous
//
#include <hip/hip_runtime.h>
#include <cstddef>

#define TT 2048
#define BB 64
#define DD 256
#define LN_EPS 1e-5f
#define WEPS 1e-4f
#define NS_ITERS 6

typedef __attribute__((ext_vector_type(8))) short bf16x8;
typedef __attribute__((ext_vector_type(4))) float f32x4;

__device__ __forceinline__ unsigned short f2bf(float f) {
  unsigned u = __float_as_uint(f);
  return (unsigned short)((u + 0x7FFFu + ((u >> 16) & 1u)) >> 16);
}
__device__ __forceinline__ float bf2f(unsigned short h) {
  return __uint_as_float(((unsigned)h) << 16);
}

// ---- K1: fused LN stats + column partial sums (single x pass) ----
// grid (16, BB); wave w handles rows c*128 + w*32 .. +31 of batch b.
__global__ __launch_bounds__(256) void prepass_kernel(const float* __restrict__ x,
    float* __restrict__ stats, float* __restrict__ part) {
  int c = blockIdx.x;
  int b = blockIdx.y;
  int tid = threadIdx.x;
  int wave = tid >> 6, lane = tid & 63;
  int rowbase = b * TT + c * 128 + wave * 32;
  const float* xb = x + (size_t)rowbase * DD + lane * 4;
  float a0 = 0.f, a1 = 0.f, a2 = 0.f, a3 = 0.f;
  for (int i = 0; i < 32; ++i) {
    float4 v = *(const float4*)&xb[(size_t)i * DD];
    float s  = v.x + v.y + v.z + v.w;
    float sq = v.x*v.x + v.y*v.y + v.z*v.z + v.w*v.w;
    #pragma unroll
    for (int off = 32; off; off >>= 1) { s += __shfl_xor(s, off); sq += __shfl_xor(sq, off); }
    float mean = s * (1.f/DD);
    float var  = fmaxf(sq * (1.f/DD) - mean*mean, 0.f);
    float rstd = rsqrtf(var + LN_EPS);
    if (lane == 0) {
      stats[2*(rowbase+i)]   = mean;
      stats[2*(rowbase+i)+1] = rstd;
    }
    a0 += (v.x - mean) * rstd;
    a1 += (v.y - mean) * rstd;
    a2 += (v.z - mean) * rstd;
    a3 += (v.w - mean) * rstd;
  }
  int pidx = c * 4 + wave;  // 0..63
  *(float4*)&part[((size_t)pidx*BB + b)*DD + lane*4] = make_float4(a0, a1, a2, a3);
}

__global__ __launch_bounds__(256) void mu_finalize_kernel(const float* __restrict__ part,
                                                          const float* __restrict__ gamma,
                                                          const float* __restrict__ beta,
                                                          float* __restrict__ mu) {
  int b = blockIdx.x;
  int d = threadIdx.x;
  float s = 0.f;
  #pragma unroll 8
  for (int c = 0; c < 64; ++c) s += part[((size_t)c*BB + b)*DD + d];
  mu[b*DD + d] = gamma[d] * s * (1.f/TT) + beta[d];
}

// ---- K3: cov via MFMA: C = Gram(Xc^T)/(T-1) + eps I, in-LDS transpose staging ----
__global__ __launch_bounds__(256) void cov_mfma(const float* __restrict__ x,
    const float* __restrict__ stats, const float* __restrict__ gamma,
    const float* __restrict__ beta, const float* __restrict__ mu,
    unsigned short* __restrict__ Ch, unsigned short* __restrict__ Cl) {
  // XCD-aware bijective remap: all 10 tiles of a batch on one XCD
  int flat = blockIdx.y * gridDim.x + blockIdx.x;  // [0,640)
  int kx = flat & 7, j = flat >> 3;                // j in [0,80)
  int b = (kx << 3) + j / 10;
  int tile = j - (j / 10) * 10;
  int p = 0, t = tile;
  while (t >= 4 - p) { t -= (4 - p); ++p; }
  int q = p + t;
  int i0 = p * 64, j0 = q * 64;
  bool diag = (p == q);

  __shared__ unsigned short sm[16384];
  unsigned short* sAh = sm;
  unsigned short* sAl = sm + 4096;
  unsigned short* sBh = sm + 8192;
  unsigned short* sBl = sm + 12288;
  __shared__ float sGi[64], sBi[64], sGj[64], sBj[64];

  int tid = threadIdx.x;
  const float* mub = mu + (size_t)b*DD;
  if (tid < 64) {
    sGi[tid] = gamma[i0+tid]; sBi[tid] = beta[i0+tid] - mub[i0+tid];
    sGj[tid] = gamma[j0+tid]; sBj[tid] = beta[j0+tid] - mub[j0+tid];
  }
  __syncthreads();

  int wave = tid >> 6, lane = tid & 63;
  int lr = lane & 15, lg = lane >> 4;
  int tl = tid >> 2;
  int d4 = (tid & 3) * 16;
  const float* xb  = x + (size_t)b*TT*DD;
  const float* stb = stats + (size_t)b*TT*2;

  f32x4 acc[4] = {};

  for (int k0 = 0; k0 < TT; k0 += 64) {
    int tg = k0 + tl;
    float mean = stb[2*tg], rstd = stb[2*tg+1];
    {
      const float* xr = xb + (size_t)tg*DD + i0 + d4;
      #pragma unroll
      for (int qq = 0; qq < 4; ++qq) {
        float4 v = *(const float4*)&xr[qq*4];
        float vv[4] = {v.x, v.y, v.z, v.w};
        #pragma unroll
        for (int e2 = 0; e2 < 4; ++e2) {
          int d = d4 + qq*4 + e2;
          float xv = (vv[e2] - mean) * rstd * sGi[d] + sBi[d];
          unsigned short h = f2bf(xv), l = f2bf(xv - bf2f(h));
          int addr = d*64 + ((((tl>>3) ^ (d&7) ^ ((d>>3)&7)) & 7) << 3) + (tl & 7);
          sAh[addr] = h; sAl[addr] = l;
        }
      }
    }
    if (!diag) {
      const float* xr = xb + (size_t)tg*DD + j0 + d4;
      #pragma unroll
      for (int qq = 0; qq < 4; ++qq) {
        float4 v = *(const float4*)&xr[qq*4];
        float vv[4] = {v.x, v.y, v.z, v.w};
        #pragma unroll
        for (int e2 = 0; e2 < 4; ++e2) {
          int d = d4 + qq*4 + e2;
          float xv = (vv[e2] - mean) * rstd * sGj[d] + sBj[d];
          unsigned short h = f2bf(xv), l = f2bf(xv - bf2f(h));
          int addr = d*64 + ((((tl>>3) ^ (d&7) ^ ((d>>3)&7)) & 7) << 3) + (tl & 7);
          sBh[addr] = h; sBl[addr] = l;
        }
      }
    }
    __syncthreads();
    const unsigned short* pBh = diag ? sAh : sBh;
    const unsigned short* pBl = diag ? sAl : sBl;
    #pragma unroll
    for (int ks = 0; ks < 2; ++ks) {
      int rowA = wave*16 + lr;
      int cc = ks*4 + lg;
      int aoff = rowA*64 + (((cc ^ (rowA&7) ^ ((rowA>>3)&7)) & 7) << 3);
      bf16x8 ahi = *(const bf16x8*)&sAh[aoff];
      bf16x8 alo = *(const bf16x8*)&sAl[aoff];
      #pragma unroll
      for (int n = 0; n < 4; ++n) {
        int rowB = n*16 + lr;
        int boff = rowB*64 + (((cc ^ (rowB&7) ^ ((rowB>>3)&7)) & 7) << 3);
        bf16x8 bhi = *(const bf16x8*)&pBh[boff];
        bf16x8 blo = *(const bf16x8*)&pBl[boff];
        acc[n] = __builtin_amdgcn_mfma_f32_16x16x32_bf16(ahi, bhi, acc[n], 0, 0, 0);
        acc[n] = __builtin_amdgcn_mfma_f32_16x16x32_bf16(ahi, blo, acc[n], 0, 0, 0);
        acc[n] = __builtin_amdgcn_mfma_f32_16x16x32_bf16(alo, bhi, acc[n], 0, 0, 0);
      }
    }
    __syncthreads();
  }

  float* sC = (float*)sm;
  #pragma unroll
  for (int n = 0; n < 4; ++n)
    #pragma unroll
    for (int r = 0; r < 4; ++r)
      sC[(wave*16 + lg*4 + r)*65 + n*16 + lr] = acc[n][r];
  __syncthreads();
  unsigned short* Chb = Ch + (size_t)b*DD*DD;
  unsigned short* Clb = Cl + (size_t)b*DD*DD;
  const float invTm1 = 1.f / (float)(TT - 1);
  int row = tid >> 2, cb = (tid & 3) * 16;
  int gi = i0 + row;
  unsigned short hv[16], lv[16];
  #pragma unroll
  for (int e = 0; e < 16; ++e) {
    float v = sC[row*65 + cb + e] * invTm1;
    int gj = j0 + cb + e;
    if (gi == gj) v += WEPS;
    hv[e] = f2bf(v);
    lv[e] = f2bf(v - bf2f(hv[e]));
    if (!diag) { Chb[(size_t)gj*DD + gi] = hv[e]; Clb[(size_t)gj*DD + gi] = lv[e]; }
  }
  size_t go = (size_t)gi*DD + j0 + cb;
  *(bf16x8*)&Chb[go]     = *(bf16x8*)&hv[0];
  *(bf16x8*)&Chb[go + 8] = *(bf16x8*)&hv[8];
  *(bf16x8*)&Clb[go]     = *(bf16x8*)&lv[0];
  *(bf16x8*)&Clb[go + 8] = *(bf16x8*)&lv[8];
}

// ---- K3b: power iteration in LDS (hi-plane only); s = 1.12 * ||C v|| ----
__global__ __launch_bounds__(256) void power_kernel(
    const unsigned short* __restrict__ Ch, float* __restrict__ sbuf) {
  int b = blockIdx.x, tid = threadIdx.x;
  __shared__ unsigned short sC[DD*DD];   // 128 KB
  __shared__ float v[DD];
  __shared__ float red[4];
  const unsigned short* Cb = Ch + (size_t)b*DD*DD;
  #pragma unroll
  for (int i = 0; i < 32; ++i) {
    int chunkid = i*256 + tid;           // 0..8191
    int r = chunkid >> 5, ch = chunkid & 31;
    bf16x8 qv = *(const bf16x8*)&Cb[(size_t)chunkid*8];
    *(bf16x8*)&sC[r*256 + ((ch ^ (r & 7)) << 3)] = qv;
  }
  unsigned u = (unsigned)tid * 2654435761u;
  v[tid] = 0.5f + (float)((u >> 9) & 1023) * (1.f/1024.f);
  __syncthreads();
  float lam = 1.f;
  for (int it = 0; it < 10; ++it) {
    float w = 0.f;
    #pragma unroll
    for (int ch = 0; ch < 32; ++ch) {
      bf16x8 hq = *(const bf16x8*)&sC[tid*256 + ((ch ^ (tid & 7)) << 3)];
      const float* vp = &v[ch*8];
      #pragma unroll
      for (int e = 0; e < 8; ++e) w += bf2f((unsigned short)hq[e]) * vp[e];
    }
    float ssq = w * w;
    #pragma unroll
    for (int off = 32; off; off >>= 1) ssq += __shfl_xor(ssq, off);
    if ((tid & 63) == 0) red[tid >> 6] = ssq;
    __syncthreads();
    float nrm = sqrtf(red[0] + red[1] + red[2] + red[3]);
    lam = nrm;
    v[tid] = w / nrm;
    __syncthreads();
  }
  if (tid == 0) sbuf[b] = lam * 1.12f;
}

// ---- K4: Y = C/s (re-split in place), Z = I ----
__global__ __launch_bounds__(256) void ns_init_kernel(unsigned short* __restrict__ Yh,
    unsigned short* __restrict__ Yl, unsigned short* __restrict__ Zh,
    unsigned short* __restrict__ Zl, const float* __restrict__ sbuf) {
  int b = blockIdx.y;
  int e = blockIdx.x * 256 + threadIdx.x;
  float invs = 1.f / sbuf[b];
  size_t idx = (size_t)b*DD*DD + e;
  float y = (bf2f(Yh[idx]) + bf2f(Yl[idx])) * invs;
  unsigned short h = f2bf(y);
  Yh[idx] = h;
  Yl[idx] = f2bf(y - bf2f(h));
  bool dg = (e >> 8) == (e & 255);
  Zh[idx] = dg ? (unsigned short)0x3F80 : (unsigned short)0;
  Zl[idx] = 0;
}

// ---- K5: 128x128-tile MFMA split-bf16 GEMM body (symmetric operands) ----
__device__ __forceinline__ void bgemm_tile2(
    const unsigned short* __restrict__ Ah, const unsigned short* __restrict__ Al,
    const unsigned short* __restrict__ Bh, const unsigned short* __restrict__ Bl,
    unsigned short* __restrict__ Ch, unsigned short* __restrict__ Cl,
    float alpha, float diagBeta, int tilex, int b, unsigned short* sm) {
  unsigned short* sAh = sm;
  unsigned short* sAl = sm + 8192;
  unsigned short* sBh = sm + 16384;
  unsigned short* sBl = sm + 24576;

  const int tid = threadIdx.x;
  const int i0g = (tilex >> 1) * 128, j0g = (tilex & 1) * 128;
  const size_t mb = (size_t)b * DD * DD;
  const int wave = tid >> 6, lane = tid & 63;
  const int wr = wave >> 2, wc = wave & 3;
  const int lr = lane & 15, lg = lane >> 4;
  const int r0 = tid >> 3;
  const int c0 = tid & 7;

  f32x4 acc[8] = {};

  for (int k0 = 0; k0 < DD; k0 += 64) {
    #pragma unroll
    for (int p = 0; p < 2; ++p) {
      int row = r0 + p * 64;
      int ld = row * 64 + ((c0 ^ (row & 7)) * 8);
      size_t ga = mb + (size_t)(i0g + row) * DD + k0 + c0 * 8;
      size_t gb = mb + (size_t)(j0g + row) * DD + k0 + c0 * 8;  // B symmetric
      *(bf16x8*)&sAh[ld] = *(const bf16x8*)&Ah[ga];
      *(bf16x8*)&sAl[ld] = *(const bf16x8*)&Al[ga];
      *(bf16x8*)&sBh[ld] = *(const bf16x8*)&Bh[gb];
      *(bf16x8*)&sBl[ld] = *(const bf16x8*)&Bl[gb];
    }
    __syncthreads();
    #pragma unroll
    for (int ks = 0; ks < 2; ++ks) {
      int cc = ks * 4 + lg;
      bf16x8 bh[2], bl[2];
      #pragma unroll
      for (int n = 0; n < 2; ++n) {
        int rowB = wc * 32 + n * 16 + lr;
        int boff = rowB * 64 + ((cc ^ (rowB & 7)) * 8);
        bh[n] = *(const bf16x8*)&sBh[boff];
        bl[n] = *(const bf16x8*)&sBl[boff];
      }
      #pragma unroll
      for (int m = 0; m < 4; ++m) {
        int rowA = wr * 64 + m * 16 + lr;
        int aoff = rowA * 64 + ((cc ^ (rowA & 7)) * 8);
        bf16x8 ah = *(const bf16x8*)&sAh[aoff];
        bf16x8 al = *(const bf16x8*)&sAl[aoff];
        #pragma unroll
        for (int n = 0; n < 2; ++n) {
          acc[m*2+n] = __builtin_amdgcn_mfma_f32_16x16x32_bf16(ah, bh[n], acc[m*2+n], 0, 0, 0);
          acc[m*2+n] = __builtin_amdgcn_mfma_f32_16x16x32_bf16(ah, bl[n], acc[m*2+n], 0, 0, 0);
          acc[m*2+n] = __builtin_amdgcn_mfma_f32_16x16x32_bf16(al, bh[n], acc[m*2+n], 0, 0, 0);
        }
      }
    }
    __syncthreads();
  }

  #pragma unroll
  for (int m = 0; m < 4; ++m) {
    #pragma unroll
    for (int n = 0; n < 2; ++n) {
      int col = j0g + wc * 32 + n * 16 + lr;
      int row0 = i0g + wr * 64 + m * 16 + lg * 4;
      #pragma unroll
      for (int r = 0; r < 4; ++r) {
        float vv = alpha * acc[m*2+n][r];
        int row = row0 + r;
        if (row == col) vv += diagBeta;
        unsigned short h = f2bf(vv), l = f2bf(vv - bf2f(h));
        Ch[mb + (size_t)row * DD + col] = h;
        Cl[mb + (size_t)row * DD + col] = l;
      }
    }
  }
}

__global__ __launch_bounds__(512) void bgemm_mfma2(
    const unsigned short* __restrict__ Ah, const unsigned short* __restrict__ Al,
    const unsigned short* __restrict__ Bh, const unsigned short* __restrict__ Bl,
    unsigned short* __restrict__ Ch, unsigned short* __restrict__ Cl,
    float alpha, float diagBeta) {
  __shared__ unsigned short sm[32768];
  int flat = blockIdx.y * gridDim.x + blockIdx.x;  // [0,256)
  int kx = flat & 7, j = flat >> 3;                // j in [0,32)
  int b = (kx << 3) + (j >> 2);
  int tile = j & 3;
  bgemm_tile2(Ah, Al, Bh, Bl, Ch, Cl, alpha, diagBeta, tile, b, sm);
}

__global__ __launch_bounds__(512) void bgemm_dual2(
    const unsigned short* __restrict__ A0h, const unsigned short* __restrict__ A0l,
    const unsigned short* __restrict__ B0h, const unsigned short* __restrict__ B0l,
    unsigned short* __restrict__ C0h, unsigned short* __restrict__ C0l,
    const unsigned short* __restrict__ A1h, const unsigned short* __restrict__ A1l,
    const unsigned short* __restrict__ B1h, const unsigned short* __restrict__ B1l,
    unsigned short* __restrict__ C1h, unsigned short* __restrict__ C1l) {
  __shared__ unsigned short sm[32768];
  int flat = blockIdx.y * gridDim.x + blockIdx.x;  // [0,512)
  int kx = flat & 7, j = flat >> 3;                // j in [0,64)
  int b = (kx << 3) + (j >> 3);
  int t8 = j & 7;
  int half = t8 >> 2, tile = t8 & 3;
  if (half == 0)
    bgemm_tile2(A0h, A0l, B0h, B0l, C0h, C0l, 0.5f, 0.f, tile, b, sm);
  else
    bgemm_tile2(A1h, A1l, B1h, B1l, C1h, C1l, 0.5f, 0.f, tile, b, sm);
}

// ---- K6: out = Xc @ (Z / sqrt(s)) via MFMA (Z symmetric -> row-fed B) ----
__global__ __launch_bounds__(256) void out_mfma(const float* __restrict__ x,
    const float* __restrict__ stats, const float* __restrict__ gamma,
    const float* __restrict__ beta, const float* __restrict__ mu,
    const unsigned short* __restrict__ Zh, const unsigned short* __restrict__ Zl,
    const float* __restrict__ sbuf, float* __restrict__ out) {
  int flat = blockIdx.y * gridDim.x + blockIdx.x;  // [0,8192)
  int kx = flat & 7, j = flat >> 3;                // j in [0,1024)
  int b = (kx << 3) + (j >> 7);
  int tile = j & 127;
  int t0 = (tile >> 2) * 64, f0 = (tile & 3) * 64;
  __shared__ unsigned short sm[16384];
  unsigned short* sAh = sm;
  unsigned short* sAl = sm + 4096;
  unsigned short* sBh = sm + 8192;
  unsigned short* sBl = sm + 12288;
  __shared__ float sG[256], sBs[256];

  int tid = threadIdx.x;
  sG[tid] = gamma[tid];
  sBs[tid] = beta[tid] - mu[(size_t)b*DD + tid];
  __syncthreads();

  const int wave = tid >> 6, lane = tid & 63;
  const int lr = lane & 15, lg = lane >> 4;
  const int r0 = tid >> 3, c0 = tid & 7;
  const float* xb  = x + (size_t)b*TT*DD;
  const float* stb = stats + (size_t)b*TT*2;
  const unsigned short* Zhb = Zh + (size_t)b*DD*DD;
  const unsigned short* Zlb = Zl + (size_t)b*DD*DD;

  f32x4 acc[4] = {};

  for (int k0 = 0; k0 < DD; k0 += 64) {
    #pragma unroll
    for (int p = 0; p < 2; ++p) {
      int row = r0 + p * 32;
      int trow = t0 + row;
      float mean = stb[2*trow], rstd = stb[2*trow+1];
      const float* xr = xb + (size_t)trow*DD + k0 + c0*8;
      unsigned short h8[8], l8[8];
      #pragma unroll
      for (int qq = 0; qq < 2; ++qq) {
        float4 v = *(const float4*)&xr[qq*4];
        float vv[4] = {v.x, v.y, v.z, v.w};
        #pragma unroll
        for (int e2 = 0; e2 < 4; ++e2) {
          int d = k0 + c0*8 + qq*4 + e2;
          float xv = (vv[e2] - mean) * rstd * sG[d] + sBs[d];
          h8[qq*4+e2] = f2bf(xv);
          l8[qq*4+e2] = f2bf(xv - bf2f(h8[qq*4+e2]));
        }
      }
      int ld = row * 64 + ((c0 ^ (row & 7)) * 8);
      *(bf16x8*)&sAh[ld] = *(bf16x8*)&h8[0];
      *(bf16x8*)&sAl[ld] = *(bf16x8*)&l8[0];
      size_t gz = (size_t)(f0 + row) * DD + k0 + c0 * 8;
      *(bf16x8*)&sBh[ld] = *(const bf16x8*)&Zhb[gz];
      *(bf16x8*)&sBl[ld] = *(const bf16x8*)&Zlb[gz];
    }
    __syncthreads();
    #pragma unroll
    for (int ks = 0; ks < 2; ++ks) {
      int rowA = wave * 16 + lr;
      int cc = ks * 4 + lg;
      int aoff = rowA * 64 + ((cc ^ (rowA & 7)) * 8);
      bf16x8 ahi = *(const bf16x8*)&sAh[aoff];
      bf16x8 alo = *(const bf16x8*)&sAl[aoff];
      #pragma unroll
      for (int n = 0; n < 4; ++n) {
        int rowB = n * 16 + lr;
        int boff = rowB * 64 + ((cc ^ (rowB & 7)) * 8);
        bf16x8 bhi = *(const bf16x8*)&sBh[boff];
        bf16x8 blo = *(const bf16x8*)&sBl[boff];
        acc[n] = __builtin_amdgcn_mfma_f32_16x16x32_bf16(ahi, bhi, acc[n], 0, 0, 0);
        acc[n] = __builtin_amdgcn_mfma_f32_16x16x32_bf16(ahi, blo, acc[n], 0, 0, 0);
        acc[n] = __builtin_amdgcn_mfma_f32_16x16x32_bf16(alo, bhi, acc[n], 0, 0, 0);
      }
    }
    __syncthreads();
  }

  float rs = rsqrtf(sbuf[b]);
  float* ob = out + (size_t)b*TT*DD;
  #pragma unroll
  for (int n = 0; n < 4; ++n)
    #pragma unroll
    for (int r = 0; r < 4; ++r)
      ob[(size_t)(t0 + wave*16 + lg*4 + r)*DD + f0 + n*16 + lr] = acc[n][r] * rs;
}

extern "C" void kernel_launch(void* const* d_in, const int* in_sizes, int n_in,
                              void* d_out, int out_size, void* d_ws, size_t ws_size,
                              hipStream_t stream) {
  const float* x     = (const float*)d_in[0];
  const float* gamma = (const float*)d_in[1];
  const float* beta  = (const float*)d_in[2];
  float* out = (float*)d_out;

  float* wsf   = (float*)d_ws;
  float* stats = wsf;                      // 262144 floats
  float* mu    = wsf + 262144;             // 16384
  float* sbuf  = wsf + 278528;             // 64
  unsigned short* nsb = (unsigned short*)(wsf + 278784);  // 16B aligned
  const size_t MATU = (size_t)BB * DD * DD;               // 4194304 ushorts/plane
  unsigned short *H[5], *L[5];
  for (int k = 0; k < 5; ++k) { H[k] = nsb + (size_t)k * 2 * MATU; L[k] = H[k] + MATU; }
  float* part = (float*)H[4];              // aliased: dead before buffer-4 first write

  prepass_kernel<<<dim3(16, BB), 256, 0, stream>>>(x, stats, part);
  mu_finalize_kernel<<<BB, 256, 0, stream>>>(part, gamma, beta, mu);
  cov_mfma<<<dim3(10, BB), 256, 0, stream>>>(x, stats, gamma, beta, mu, H[0], L[0]);
  power_kernel<<<BB, 256, 0, stream>>>(H[0], sbuf);
  ns_init_kernel<<<dim3(256, BB), 256, 0, stream>>>(H[0], L[0], H[1], L[1], sbuf);

  int y = 0, z = 1, m = 2, s = 3, u = 4;
  for (int it = 0; it < NS_ITERS - 1; ++it) {
    bgemm_mfma2<<<dim3(4, BB), 512, 0, stream>>>(H[z], L[z], H[y], L[y], H[m], L[m], -1.f, 3.f);
    bgemm_dual2<<<dim3(8, BB), 512, 0, stream>>>(H[y], L[y], H[m], L[m], H[s], L[s],
                                                 H[m], L[m], H[z], L[z], H[u], L[u]);
    int oy = y, oz = z;
    y = s; z = u; s = oy; u = oz;
  }
  bgemm_mfma2<<<dim3(4, BB), 512, 0, stream>>>(H[z], L[z], H[y], L[y], H[m], L[m], -1.f, 3.f);
  bgemm_mfma2<<<dim3(4, BB), 512, 0, stream>>>(H[m], L[m], H[z], L[z], H[s], L[s], 0.5f, 0.f);
  z = s;

  out_mfma<<<dim3(128, BB), 256, 0, stream>>>(x, stats, gamma, beta, mu, H[z], L[z], sbuf, out);
}

// Round 7
// 424.451 us; speedup vs baseline: 6.7352x; 1.0897x over previous
//
#include <hip/hip_runtime.h>
#include <cstddef>

#define TT 2048
#define BB 64
#define DD 256
#define LN_EPS 1e-5f
#define WEPS 1e-4f
#define NS_ITERS 6

typedef __attribute__((ext_vector_type(8))) short bf16x8;
typedef __attribute__((ext_vector_type(4))) float f32x4;
typedef __attribute__((ext_vector_type(8))) _Float16 f16x8;
typedef __attribute__((ext_vector_type(4))) _Float16 f16x4;

__device__ __forceinline__ unsigned short f2bf(float f) {
  unsigned u = __float_as_uint(f);
  return (unsigned short)((u + 0x7FFFu + ((u >> 16) & 1u)) >> 16);
}
__device__ __forceinline__ float bf2f(unsigned short h) {
  return __uint_as_float(((unsigned)h) << 16);
}
// async global->LDS, 16B per lane; dest must be wave-uniform base (+lane*16 by HW)
__device__ __forceinline__ void gload16(unsigned short* lds, const unsigned short* g) {
  __builtin_amdgcn_global_load_lds(
      (const __attribute__((address_space(1))) void*)g,
      (__attribute__((address_space(3))) void*)lds, 16, 0, 0);
}

// ---- K1: fused LN stats + column partial sums (single x pass) ----
__global__ __launch_bounds__(256) void prepass_kernel(const float* __restrict__ x,
    float* __restrict__ stats, float* __restrict__ part) {
  int c = blockIdx.x;
  int b = blockIdx.y;
  int tid = threadIdx.x;
  int wave = tid >> 6, lane = tid & 63;
  int rowbase = b * TT + c * 128 + wave * 32;
  const float* xb = x + (size_t)rowbase * DD + lane * 4;
  float a0 = 0.f, a1 = 0.f, a2 = 0.f, a3 = 0.f;
  for (int i = 0; i < 32; ++i) {
    float4 v = *(const float4*)&xb[(size_t)i * DD];
    float s  = v.x + v.y + v.z + v.w;
    float sq = v.x*v.x + v.y*v.y + v.z*v.z + v.w*v.w;
    #pragma unroll
    for (int off = 32; off; off >>= 1) { s += __shfl_xor(s, off); sq += __shfl_xor(sq, off); }
    float mean = s * (1.f/DD);
    float var  = fmaxf(sq * (1.f/DD) - mean*mean, 0.f);
    float rstd = rsqrtf(var + LN_EPS);
    if (lane == 0) {
      stats[2*(rowbase+i)]   = mean;
      stats[2*(rowbase+i)+1] = rstd;
    }
    a0 += (v.x - mean) * rstd;
    a1 += (v.y - mean) * rstd;
    a2 += (v.z - mean) * rstd;
    a3 += (v.w - mean) * rstd;
  }
  int pidx = c * 4 + wave;
  *(float4*)&part[((size_t)pidx*BB + b)*DD + lane*4] = make_float4(a0, a1, a2, a3);
}

__global__ __launch_bounds__(256) void mu_finalize_kernel(const float* __restrict__ part,
                                                          const float* __restrict__ gamma,
                                                          const float* __restrict__ beta,
                                                          float* __restrict__ mu) {
  int b = blockIdx.x;
  int d = threadIdx.x;
  float s = 0.f;
  #pragma unroll 8
  for (int c = 0; c < 64; ++c) s += part[((size_t)c*BB + b)*DD + d];
  mu[b*DD + d] = gamma[d] * s * (1.f/TT) + beta[d];
}

// ---- K3: cov via fp16 MFMA: C = Gram(Xc^T)/(T-1) + eps I ----
// fp16 single-plane input (rel err 2^-11 -> out err ~0.02 abs, threshold 0.107).
// Staging: 4t x 4d register transpose, f16x4 (8B) swizzled LDS stores.
__global__ __launch_bounds__(256) void cov_mfma(const float* __restrict__ x,
    const float* __restrict__ stats, const float* __restrict__ gamma,
    const float* __restrict__ beta, const float* __restrict__ mu,
    unsigned short* __restrict__ Ch, unsigned short* __restrict__ Cl) {
  int flat = blockIdx.y * gridDim.x + blockIdx.x;  // [0,640); XCD-bijective remap
  int kx = flat & 7, j = flat >> 3;
  int b = (kx << 3) + j / 10;
  int tile = j - (j / 10) * 10;
  int p = 0, t = tile;
  while (t >= 4 - p) { t -= (4 - p); ++p; }
  int q = p + t;
  int i0 = p * 64, j0 = q * 64;
  bool diag = (p == q);

  __shared__ unsigned short sm[8448];   // sA 4096, sB 4096; epilogue floats (4160) fit
  unsigned short* sA = sm;
  unsigned short* sB = sm + 4096;
  __shared__ float sGi[64], sBi[64], sGj[64], sBj[64];

  int tid = threadIdx.x;
  const float* mub = mu + (size_t)b*DD;
  if (tid < 64) {
    sGi[tid] = gamma[i0+tid]; sBi[tid] = beta[i0+tid] - mub[i0+tid];
    sGj[tid] = gamma[j0+tid]; sBj[tid] = beta[j0+tid] - mub[j0+tid];
  }
  __syncthreads();

  int wave = tid >> 6, lane = tid & 63;
  int lr = lane & 15, lg = lane >> 4;
  int tg4 = tid >> 4;       // t-group (4 rows)
  int dg  = tid & 15;       // d-group (4 cols)
  int d0 = dg * 4;
  const float* xb  = x + (size_t)b*TT*DD;
  const float* stb = stats + (size_t)b*TT*2;

  float4 gi4 = *(const float4*)&sGi[d0];
  float4 bi4 = *(const float4*)&sBi[d0];
  float4 gj4 = *(const float4*)&sGj[d0];
  float4 bj4 = *(const float4*)&sBj[d0];

  // swizzled write indices (ushort units) for the 4 d's; chunk16 = tg4>>1, half = tg4&1
  int ch16 = tg4 >> 1, half = tg4 & 1;
  int widx[4];
  #pragma unroll
  for (int jj = 0; jj < 4; ++jj) {
    int dl = d0 + jj;
    int swz = (ch16 ^ (dl & 7) ^ ((dl >> 3) & 7)) & 7;
    widx[jj] = dl*64 + swz*8 + half*4;
  }

  f32x4 acc[4] = {};

  for (int k0 = 0; k0 < TT; k0 += 64) {
    int trow = k0 + tg4 * 4;
    float4 s01 = *(const float4*)&stb[2*trow];      // m0,r0,m1,r1
    float4 s23 = *(const float4*)&stb[2*trow + 4];  // m2,r2,m3,r3
    float mm[4] = {s01.x, s01.z, s23.x, s23.z};
    float rr[4] = {s01.y, s01.w, s23.y, s23.w};
    {
      _Float16 va[4][4];
      #pragma unroll
      for (int i = 0; i < 4; ++i) {
        float4 v = *(const float4*)&xb[(size_t)(trow+i)*DD + i0 + d0];
        va[i][0] = (_Float16)(((v.x - mm[i]) * rr[i]) * gi4.x + bi4.x);
        va[i][1] = (_Float16)(((v.y - mm[i]) * rr[i]) * gi4.y + bi4.y);
        va[i][2] = (_Float16)(((v.z - mm[i]) * rr[i]) * gi4.z + bi4.z);
        va[i][3] = (_Float16)(((v.w - mm[i]) * rr[i]) * gi4.w + bi4.w);
      }
      #pragma unroll
      for (int jj = 0; jj < 4; ++jj) {
        f16x4 w = {va[0][jj], va[1][jj], va[2][jj], va[3][jj]};
        *(f16x4*)&sA[widx[jj]] = w;
      }
    }
    if (!diag) {
      _Float16 vb[4][4];
      #pragma unroll
      for (int i = 0; i < 4; ++i) {
        float4 v = *(const float4*)&xb[(size_t)(trow+i)*DD + j0 + d0];
        vb[i][0] = (_Float16)(((v.x - mm[i]) * rr[i]) * gj4.x + bj4.x);
        vb[i][1] = (_Float16)(((v.y - mm[i]) * rr[i]) * gj4.y + bj4.y);
        vb[i][2] = (_Float16)(((v.z - mm[i]) * rr[i]) * gj4.z + bj4.z);
        vb[i][3] = (_Float16)(((v.w - mm[i]) * rr[i]) * gj4.w + bj4.w);
      }
      #pragma unroll
      for (int jj = 0; jj < 4; ++jj) {
        f16x4 w = {vb[0][jj], vb[1][jj], vb[2][jj], vb[3][jj]};
        *(f16x4*)&sB[widx[jj]] = w;
      }
    }
    __syncthreads();
    const unsigned short* pB = diag ? sA : sB;
    #pragma unroll
    for (int ks = 0; ks < 2; ++ks) {
      int rowA = wave*16 + lr;
      int cc = ks*4 + lg;
      int aoff = rowA*64 + (((cc ^ (rowA&7) ^ ((rowA>>3)&7)) & 7) << 3);
      f16x8 av = *(const f16x8*)&sA[aoff];
      #pragma unroll
      for (int n = 0; n < 4; ++n) {
        int rowB = n*16 + lr;
        int boff = rowB*64 + (((cc ^ (rowB&7) ^ ((rowB>>3)&7)) & 7) << 3);
        f16x8 bv = *(const f16x8*)&pB[boff];
        acc[n] = __builtin_amdgcn_mfma_f32_16x16x32_f16(av, bv, acc[n], 0, 0, 0);
      }
    }
    __syncthreads();
  }

  float* sC = (float*)sm;
  #pragma unroll
  for (int n = 0; n < 4; ++n)
    #pragma unroll
    for (int r = 0; r < 4; ++r)
      sC[(wave*16 + lg*4 + r)*65 + n*16 + lr] = acc[n][r];
  __syncthreads();
  unsigned short* Chb = Ch + (size_t)b*DD*DD;
  unsigned short* Clb = Cl + (size_t)b*DD*DD;
  const float invTm1 = 1.f / (float)(TT - 1);
  int row = tid >> 2, cb = (tid & 3) * 16;
  int gi = i0 + row;
  unsigned short hv[16], lv[16];
  #pragma unroll
  for (int e = 0; e < 16; ++e) {
    float v = sC[row*65 + cb + e] * invTm1;
    int gj = j0 + cb + e;
    if (gi == gj) v += WEPS;
    hv[e] = f2bf(v);
    lv[e] = f2bf(v - bf2f(hv[e]));
    if (!diag) { Chb[(size_t)gj*DD + gi] = hv[e]; Clb[(size_t)gj*DD + gi] = lv[e]; }
  }
  size_t go = (size_t)gi*DD + j0 + cb;
  *(bf16x8*)&Chb[go]     = *(bf16x8*)&hv[0];
  *(bf16x8*)&Chb[go + 8] = *(bf16x8*)&hv[8];
  *(bf16x8*)&Clb[go]     = *(bf16x8*)&lv[0];
  *(bf16x8*)&Clb[go + 8] = *(bf16x8*)&lv[8];
}

// ---- K3b: power iteration in LDS (hi-plane only); s = 1.12 * ||C v|| ----
__global__ __launch_bounds__(256) void power_kernel(
    const unsigned short* __restrict__ Ch, float* __restrict__ sbuf) {
  int b = blockIdx.x, tid = threadIdx.x;
  __shared__ unsigned short sC[DD*DD];   // 128 KB
  __shared__ float v[DD];
  __shared__ float red[4];
  const unsigned short* Cb = Ch + (size_t)b*DD*DD;
  #pragma unroll
  for (int i = 0; i < 32; ++i) {
    int chunkid = i*256 + tid;
    int r = chunkid >> 5, ch = chunkid & 31;
    bf16x8 qv = *(const bf16x8*)&Cb[(size_t)chunkid*8];
    *(bf16x8*)&sC[r*256 + ((ch ^ (r & 7)) << 3)] = qv;
  }
  unsigned u = (unsigned)tid * 2654435761u;
  v[tid] = 0.5f + (float)((u >> 9) & 1023) * (1.f/1024.f);
  __syncthreads();
  float lam = 1.f;
  for (int it = 0; it < 10; ++it) {
    float w = 0.f;
    #pragma unroll
    for (int ch = 0; ch < 32; ++ch) {
      bf16x8 hq = *(const bf16x8*)&sC[tid*256 + ((ch ^ (tid & 7)) << 3)];
      const float* vp = &v[ch*8];
      #pragma unroll
      for (int e = 0; e < 8; ++e) w += bf2f((unsigned short)hq[e]) * vp[e];
    }
    float ssq = w * w;
    #pragma unroll
    for (int off = 32; off; off >>= 1) ssq += __shfl_xor(ssq, off);
    if ((tid & 63) == 0) red[tid >> 6] = ssq;
    __syncthreads();
    float nrm = sqrtf(red[0] + red[1] + red[2] + red[3]);
    lam = nrm;
    v[tid] = w / nrm;
    __syncthreads();
  }
  if (tid == 0) sbuf[b] = lam * 1.12f;
}

// ---- K4: Y = C/s (re-split in place), Z = I ----
__global__ __launch_bounds__(256) void ns_init_kernel(unsigned short* __restrict__ Yh,
    unsigned short* __restrict__ Yl, unsigned short* __restrict__ Zh,
    unsigned short* __restrict__ Zl, const float* __restrict__ sbuf) {
  int b = blockIdx.y;
  int e = blockIdx.x * 256 + threadIdx.x;
  float invs = 1.f / sbuf[b];
  size_t idx = (size_t)b*DD*DD + e;
  float y = (bf2f(Yh[idx]) + bf2f(Yl[idx])) * invs;
  unsigned short h = f2bf(y);
  Yh[idx] = h;
  Yl[idx] = f2bf(y - bf2f(h));
  bool dg = (e >> 8) == (e & 255);
  Zh[idx] = dg ? (unsigned short)0x3F80 : (unsigned short)0;
  Zl[idx] = 0;
}

// ---- K5: 128x128-tile split-bf16 MFMA GEMM, global_load_lds staging ----
// Linear LDS dest + pre-swizzled global source + swizzled read (rule: both sides).
__device__ __forceinline__ void bgemm_tile2(
    const unsigned short* __restrict__ Ah, const unsigned short* __restrict__ Al,
    const unsigned short* __restrict__ Bh, const unsigned short* __restrict__ Bl,
    unsigned short* __restrict__ Ch, unsigned short* __restrict__ Cl,
    float alpha, float diagBeta, int tilex, int b, unsigned short* sm) {
  unsigned short* sAh = sm;
  unsigned short* sAl = sm + 8192;
  unsigned short* sBh = sm + 16384;
  unsigned short* sBl = sm + 24576;

  const int tid = threadIdx.x;
  const int i0g = (tilex >> 1) * 128, j0g = (tilex & 1) * 128;
  const size_t mb = (size_t)b * DD * DD;
  const int wave = tid >> 6, lane = tid & 63;
  const int wr = wave >> 2, wc = wave & 3;
  const int lr = lane & 15, lg = lane >> 4;

  f32x4 acc[8] = {};

  for (int k0 = 0; k0 < DD; k0 += 64) {
    #pragma unroll
    for (int p2 = 0; p2 < 2; ++p2) {
      int slot = tid + p2 * 512;
      int row = slot >> 3, c = slot & 7;
      int srcc = (c ^ (row & 7)) << 3;             // pre-swizzled source chunk
      size_t ga = mb + (size_t)(i0g + row) * DD + k0 + srcc;
      size_t gb = mb + (size_t)(j0g + row) * DD + k0 + srcc;  // B symmetric
      int base = (wave * 64 + p2 * 512) * 8;       // wave-uniform dest (ushorts)
      gload16(&sAh[base], Ah + ga);
      gload16(&sAl[base], Al + ga);
      gload16(&sBh[base], Bh + gb);
      gload16(&sBl[base], Bl + gb);
    }
    __syncthreads();   // drains vmcnt (gload_lds) for all waves
    #pragma unroll
    for (int ks = 0; ks < 2; ++ks) {
      int cc = ks * 4 + lg;
      bf16x8 bh[2], bl[2];
      #pragma unroll
      for (int n = 0; n < 2; ++n) {
        int rowB = wc * 32 + n * 16 + lr;
        int boff = rowB * 64 + ((cc ^ (rowB & 7)) * 8);
        bh[n] = *(const bf16x8*)&sBh[boff];
        bl[n] = *(const bf16x8*)&sBl[boff];
      }
      #pragma unroll
      for (int m = 0; m < 4; ++m) {
        int rowA = wr * 64 + m * 16 + lr;
        int aoff = rowA * 64 + ((cc ^ (rowA & 7)) * 8);
        bf16x8 ah = *(const bf16x8*)&sAh[aoff];
        bf16x8 al = *(const bf16x8*)&sAl[aoff];
        #pragma unroll
        for (int n = 0; n < 2; ++n) {
          acc[m*2+n] = __builtin_amdgcn_mfma_f32_16x16x32_bf16(ah, bh[n], acc[m*2+n], 0, 0, 0);
          acc[m*2+n] = __builtin_amdgcn_mfma_f32_16x16x32_bf16(ah, bl[n], acc[m*2+n], 0, 0, 0);
          acc[m*2+n] = __builtin_amdgcn_mfma_f32_16x16x32_bf16(al, bh[n], acc[m*2+n], 0, 0, 0);
        }
      }
    }
    __syncthreads();
  }

  #pragma unroll
  for (int m = 0; m < 4; ++m) {
    #pragma unroll
    for (int n = 0; n < 2; ++n) {
      int col = j0g + wc * 32 + n * 16 + lr;
      int row0 = i0g + wr * 64 + m * 16 + lg * 4;
      #pragma unroll
      for (int r = 0; r < 4; ++r) {
        float vv = alpha * acc[m*2+n][r];
        int row = row0 + r;
        if (row == col) vv += diagBeta;
        unsigned short h = f2bf(vv), l = f2bf(vv - bf2f(h));
        Ch[mb + (size_t)row * DD + col] = h;
        Cl[mb + (size_t)row * DD + col] = l;
      }
    }
  }
}

__global__ __launch_bounds__(512) void bgemm_mfma2(
    const unsigned short* __restrict__ Ah, const unsigned short* __restrict__ Al,
    const unsigned short* __restrict__ Bh, const unsigned short* __restrict__ Bl,
    unsigned short* __restrict__ Ch, unsigned short* __restrict__ Cl,
    float alpha, float diagBeta) {
  __shared__ unsigned short sm[32768];
  int flat = blockIdx.y * gridDim.x + blockIdx.x;
  int kx = flat & 7, j = flat >> 3;
  int b = (kx << 3) + (j >> 2);
  int tile = j & 3;
  bgemm_tile2(Ah, Al, Bh, Bl, Ch, Cl, alpha, diagBeta, tile, b, sm);
}

__global__ __launch_bounds__(512) void bgemm_dual2(
    const unsigned short* __restrict__ A0h, const unsigned short* __restrict__ A0l,
    const unsigned short* __restrict__ B0h, const unsigned short* __restrict__ B0l,
    unsigned short* __restrict__ C0h, unsigned short* __restrict__ C0l,
    const unsigned short* __restrict__ A1h, const unsigned short* __restrict__ A1l,
    const unsigned short* __restrict__ B1h, const unsigned short* __restrict__ B1l,
    unsigned short* __restrict__ C1h, unsigned short* __restrict__ C1l) {
  __shared__ unsigned short sm[32768];
  int flat = blockIdx.y * gridDim.x + blockIdx.x;
  int kx = flat & 7, j = flat >> 3;
  int b = (kx << 3) + (j >> 3);
  int t8 = j & 7;
  int half = t8 >> 2, tile = t8 & 3;
  if (half == 0)
    bgemm_tile2(A0h, A0l, B0h, B0l, C0h, C0l, 0.5f, 0.f, tile, b, sm);
  else
    bgemm_tile2(A1h, A1l, B1h, B1l, C1h, C1l, 0.5f, 0.f, tile, b, sm);
}

// ---- K6: out = Xc @ (Z / sqrt(s)); A reg-transform, B via global_load_lds ----
__global__ __launch_bounds__(256) void out_mfma(const float* __restrict__ x,
    const float* __restrict__ stats, const float* __restrict__ gamma,
    const float* __restrict__ beta, const float* __restrict__ mu,
    const unsigned short* __restrict__ Zh, const unsigned short* __restrict__ Zl,
    const float* __restrict__ sbuf, float* __restrict__ out) {
  int flat = blockIdx.y * gridDim.x + blockIdx.x;
  int kx = flat & 7, j = flat >> 3;
  int b = (kx << 3) + (j >> 7);
  int tile = j & 127;
  int t0 = (tile >> 2) * 64, f0 = (tile & 3) * 64;
  __shared__ unsigned short sm[16384];
  unsigned short* sAh = sm;
  unsigned short* sAl = sm + 4096;
  unsigned short* sBh = sm + 8192;
  unsigned short* sBl = sm + 12288;
  __shared__ float sG[256], sBs[256];

  int tid = threadIdx.x;
  sG[tid] = gamma[tid];
  sBs[tid] = beta[tid] - mu[(size_t)b*DD + tid];
  __syncthreads();

  const int wave = tid >> 6, lane = tid & 63;
  const int lr = lane & 15, lg = lane >> 4;
  const int r0 = tid >> 3, c0 = tid & 7;
  const float* xb  = x + (size_t)b*TT*DD;
  const float* stb = stats + (size_t)b*TT*2;
  const unsigned short* Zhb = Zh + (size_t)b*DD*DD;
  const unsigned short* Zlb = Zl + (size_t)b*DD*DD;

  f32x4 acc[4] = {};

  for (int k0 = 0; k0 < DD; k0 += 64) {
    #pragma unroll
    for (int p2 = 0; p2 < 2; ++p2) {
      // B (Z) via async gload: linear dest, pre-swizzled source
      int slot = tid + p2 * 256;
      int rowb = slot >> 3, cb2 = slot & 7;
      int srcc = (cb2 ^ (rowb & 7)) << 3;
      size_t gz = (size_t)(f0 + rowb) * DD + k0 + srcc;
      int base = (wave * 64 + p2 * 256) * 8;
      gload16(&sBh[base], Zhb + gz);
      gload16(&sBl[base], Zlb + gz);
      // A (Xc) transform + swizzled vector write
      int row = r0 + p2 * 32;
      int trow = t0 + row;
      float mean = stb[2*trow], rstd = stb[2*trow+1];
      const float* xr = xb + (size_t)trow*DD + k0 + c0*8;
      unsigned short h8[8], l8[8];
      #pragma unroll
      for (int qq = 0; qq < 2; ++qq) {
        float4 v = *(const float4*)&xr[qq*4];
        float vv[4] = {v.x, v.y, v.z, v.w};
        #pragma unroll
        for (int e2 = 0; e2 < 4; ++e2) {
          int d = k0 + c0*8 + qq*4 + e2;
          float xv = (vv[e2] - mean) * rstd * sG[d] + sBs[d];
          h8[qq*4+e2] = f2bf(xv);
          l8[qq*4+e2] = f2bf(xv - bf2f(h8[qq*4+e2]));
        }
      }
      int ld = row * 64 + ((c0 ^ (row & 7)) * 8);
      *(bf16x8*)&sAh[ld] = *(bf16x8*)&h8[0];
      *(bf16x8*)&sAl[ld] = *(bf16x8*)&l8[0];
    }
    __syncthreads();
    #pragma unroll
    for (int ks = 0; ks < 2; ++ks) {
      int rowA = wave * 16 + lr;
      int cc = ks * 4 + lg;
      int aoff = rowA * 64 + ((cc ^ (rowA & 7)) * 8);
      bf16x8 ahi = *(const bf16x8*)&sAh[aoff];
      bf16x8 alo = *(const bf16x8*)&sAl[aoff];
      #pragma unroll
      for (int n = 0; n < 4; ++n) {
        int rowB = n * 16 + lr;
        int boff = rowB * 64 + ((cc ^ (rowB & 7)) * 8);
        bf16x8 bhi = *(const bf16x8*)&sBh[boff];
        bf16x8 blo = *(const bf16x8*)&sBl[boff];
        acc[n] = __builtin_amdgcn_mfma_f32_16x16x32_bf16(ahi, bhi, acc[n], 0, 0, 0);
        acc[n] = __builtin_amdgcn_mfma_f32_16x16x32_bf16(ahi, blo, acc[n], 0, 0, 0);
        acc[n] = __builtin_amdgcn_mfma_f32_16x16x32_bf16(alo, bhi, acc[n], 0, 0, 0);
      }
    }
    __syncthreads();
  }

  float rs = rsqrtf(sbuf[b]);
  float* ob = out + (size_t)b*TT*DD;
  #pragma unroll
  for (int n = 0; n < 4; ++n)
    #pragma unroll
    for (int r = 0; r < 4; ++r)
      ob[(size_t)(t0 + wave*16 + lg*4 + r)*DD + f0 + n*16 + lr] = acc[n][r] * rs;
}

extern "C" void kernel_launch(void* const* d_in, const int* in_sizes, int n_in,
                              void* d_out, int out_size, void* d_ws, size_t ws_size,
                              hipStream_t stream) {
  const float* x     = (const float*)d_in[0];
  const float* gamma = (const float*)d_in[1];
  const float* beta  = (const float*)d_in[2];
  float* out = (float*)d_out;

  float* wsf   = (float*)d_ws;
  float* stats = wsf;                      // 262144 floats
  float* mu    = wsf + 262144;             // 16384
  float* sbuf  = wsf + 278528;             // 64
  unsigned short* nsb = (unsigned short*)(wsf + 278784);
  const size_t MATU = (size_t)BB * DD * DD;
  unsigned short *H[5], *L[5];
  for (int k = 0; k < 5; ++k) { H[k] = nsb + (size_t)k * 2 * MATU; L[k] = H[k] + MATU; }
  float* part = (float*)H[4];              // aliased: dead before buffer-4 first write

  prepass_kernel<<<dim3(16, BB), 256, 0, stream>>>(x, stats, part);
  mu_finalize_kernel<<<BB, 256, 0, stream>>>(part, gamma, beta, mu);
  cov_mfma<<<dim3(10, BB), 256, 0, stream>>>(x, stats, gamma, beta, mu, H[0], L[0]);
  power_kernel<<<BB, 256, 0, stream>>>(H[0], sbuf);
  ns_init_kernel<<<dim3(256, BB), 256, 0, stream>>>(H[0], L[0], H[1], L[1], sbuf);

  int y = 0, z = 1, m = 2, s = 3, u = 4;
  for (int it = 0; it < NS_ITERS - 1; ++it) {
    bgemm_mfma2<<<dim3(4, BB), 512, 0, stream>>>(H[z], L[z], H[y], L[y], H[m], L[m], -1.f, 3.f);
    bgemm_dual2<<<dim3(8, BB), 512, 0, stream>>>(H[y], L[y], H[m], L[m], H[s], L[s],
                                                 H[m], L[m], H[z], L[z], H[u], L[u]);
    int oy = y, oz = z;
    y = s; z = u; s = oy; u = oz;
  }
  bgemm_mfma2<<<dim3(4, BB), 512, 0, stream>>>(H[z], L[z], H[y], L[y], H[m], L[m], -1.f, 3.f);
  bgemm_mfma2<<<dim3(4, BB), 512, 0, stream>>>(H[m], L[m], H[z], L[z], H[s], L[s], 0.5f, 0.f);
  z = s;

  out_mfma<<<dim3(128, BB), 256, 0, stream>>>(x, stats, gamma, beta, mu, H[z], L[z], sbuf, out);
}

// Round 8
// 276.116 us; speedup vs baseline: 10.3534x; 1.5372x over previous
//
#include <hip/hip_runtime.h>
#include <cstddef>

#define TT 2048
#define BB 64
#define DD 256
#define LN_EPS 1e-5f
#define WEPS 1e-4f
#define NS_ITERS 6

typedef __attribute__((ext_vector_type(8))) short short8;
typedef __attribute__((ext_vector_type(4))) float f32x4;
typedef __attribute__((ext_vector_type(8))) _Float16 f16x8;
typedef __attribute__((ext_vector_type(4))) _Float16 f16x4;

__device__ __forceinline__ unsigned short f2h(float f) {
  _Float16 h = (_Float16)f;
  return *(unsigned short*)&h;
}
__device__ __forceinline__ float h2f(unsigned short u) {
  _Float16 h = *(_Float16*)&u;
  return (float)h;
}
// async global->LDS, 16B per lane; dest wave-uniform base (+lane*16 by HW)
__device__ __forceinline__ void gload16(unsigned short* lds, const unsigned short* g) {
  __builtin_amdgcn_global_load_lds(
      (const __attribute__((address_space(1))) void*)g,
      (__attribute__((address_space(3))) void*)lds, 16, 0, 0);
}

// ---- K1: fused LN stats + column partial sums (single x pass) ----
__global__ __launch_bounds__(256) void prepass_kernel(const float* __restrict__ x,
    float* __restrict__ stats, float* __restrict__ part) {
  int c = blockIdx.x;
  int b = blockIdx.y;
  int tid = threadIdx.x;
  int wave = tid >> 6, lane = tid & 63;
  int rowbase = b * TT + c * 128 + wave * 32;
  const float* xb = x + (size_t)rowbase * DD + lane * 4;
  float a0 = 0.f, a1 = 0.f, a2 = 0.f, a3 = 0.f;
  for (int i = 0; i < 32; ++i) {
    float4 v = *(const float4*)&xb[(size_t)i * DD];
    float s  = v.x + v.y + v.z + v.w;
    float sq = v.x*v.x + v.y*v.y + v.z*v.z + v.w*v.w;
    #pragma unroll
    for (int off = 32; off; off >>= 1) { s += __shfl_xor(s, off); sq += __shfl_xor(sq, off); }
    float mean = s * (1.f/DD);
    float var  = fmaxf(sq * (1.f/DD) - mean*mean, 0.f);
    float rstd = rsqrtf(var + LN_EPS);
    if (lane == 0) {
      stats[2*(rowbase+i)]   = mean;
      stats[2*(rowbase+i)+1] = rstd;
    }
    a0 += (v.x - mean) * rstd;
    a1 += (v.y - mean) * rstd;
    a2 += (v.z - mean) * rstd;
    a3 += (v.w - mean) * rstd;
  }
  int pidx = c * 4 + wave;
  *(float4*)&part[((size_t)pidx*BB + b)*DD + lane*4] = make_float4(a0, a1, a2, a3);
}

__global__ __launch_bounds__(256) void mu_finalize_kernel(const float* __restrict__ part,
                                                          const float* __restrict__ gamma,
                                                          const float* __restrict__ beta,
                                                          float* __restrict__ mu) {
  int b = blockIdx.x;
  int d = threadIdx.x;
  float s = 0.f;
  #pragma unroll 8
  for (int c = 0; c < 64; ++c) s += part[((size_t)c*BB + b)*DD + d];
  mu[b*DD + d] = gamma[d] * s * (1.f/TT) + beta[d];
}

// ---- K3: cov via fp16 MFMA: C = Gram(Xc^T)/(T-1) + eps I -> fp16 plane ----
__global__ __launch_bounds__(256) void cov_mfma(const float* __restrict__ x,
    const float* __restrict__ stats, const float* __restrict__ gamma,
    const float* __restrict__ beta, const float* __restrict__ mu,
    unsigned short* __restrict__ Ch) {
  int flat = blockIdx.y * gridDim.x + blockIdx.x;  // [0,640); XCD-bijective remap
  int kx = flat & 7, j = flat >> 3;
  int b = (kx << 3) + j / 10;
  int tile = j - (j / 10) * 10;
  int p = 0, t = tile;
  while (t >= 4 - p) { t -= (4 - p); ++p; }
  int q = p + t;
  int i0 = p * 64, j0 = q * 64;
  bool diag = (p == q);

  __shared__ unsigned short sm[8448];
  unsigned short* sA = sm;
  unsigned short* sB = sm + 4096;
  __shared__ float sGi[64], sBi[64], sGj[64], sBj[64];

  int tid = threadIdx.x;
  const float* mub = mu + (size_t)b*DD;
  if (tid < 64) {
    sGi[tid] = gamma[i0+tid]; sBi[tid] = beta[i0+tid] - mub[i0+tid];
    sGj[tid] = gamma[j0+tid]; sBj[tid] = beta[j0+tid] - mub[j0+tid];
  }
  __syncthreads();

  int wave = tid >> 6, lane = tid & 63;
  int lr = lane & 15, lg = lane >> 4;
  int tg4 = tid >> 4;
  int dg  = tid & 15;
  int d0 = dg * 4;
  const float* xb  = x + (size_t)b*TT*DD;
  const float* stb = stats + (size_t)b*TT*2;

  float4 gi4 = *(const float4*)&sGi[d0];
  float4 bi4 = *(const float4*)&sBi[d0];
  float4 gj4 = *(const float4*)&sGj[d0];
  float4 bj4 = *(const float4*)&sBj[d0];

  int ch16 = tg4 >> 1, half = tg4 & 1;
  int widx[4];
  #pragma unroll
  for (int jj = 0; jj < 4; ++jj) {
    int dl = d0 + jj;
    int swz = (ch16 ^ (dl & 7) ^ ((dl >> 3) & 7)) & 7;
    widx[jj] = dl*64 + swz*8 + half*4;
  }

  f32x4 acc[4] = {};

  for (int k0 = 0; k0 < TT; k0 += 64) {
    int trow = k0 + tg4 * 4;
    float4 s01 = *(const float4*)&stb[2*trow];
    float4 s23 = *(const float4*)&stb[2*trow + 4];
    float mm[4] = {s01.x, s01.z, s23.x, s23.z};
    float rr[4] = {s01.y, s01.w, s23.y, s23.w};
    {
      _Float16 va[4][4];
      #pragma unroll
      for (int i = 0; i < 4; ++i) {
        float4 v = *(const float4*)&xb[(size_t)(trow+i)*DD + i0 + d0];
        va[i][0] = (_Float16)(((v.x - mm[i]) * rr[i]) * gi4.x + bi4.x);
        va[i][1] = (_Float16)(((v.y - mm[i]) * rr[i]) * gi4.y + bi4.y);
        va[i][2] = (_Float16)(((v.z - mm[i]) * rr[i]) * gi4.z + bi4.z);
        va[i][3] = (_Float16)(((v.w - mm[i]) * rr[i]) * gi4.w + bi4.w);
      }
      #pragma unroll
      for (int jj = 0; jj < 4; ++jj) {
        f16x4 w = {va[0][jj], va[1][jj], va[2][jj], va[3][jj]};
        *(f16x4*)&sA[widx[jj]] = w;
      }
    }
    if (!diag) {
      _Float16 vb[4][4];
      #pragma unroll
      for (int i = 0; i < 4; ++i) {
        float4 v = *(const float4*)&xb[(size_t)(trow+i)*DD + j0 + d0];
        vb[i][0] = (_Float16)(((v.x - mm[i]) * rr[i]) * gj4.x + bj4.x);
        vb[i][1] = (_Float16)(((v.y - mm[i]) * rr[i]) * gj4.y + bj4.y);
        vb[i][2] = (_Float16)(((v.z - mm[i]) * rr[i]) * gj4.z + bj4.z);
        vb[i][3] = (_Float16)(((v.w - mm[i]) * rr[i]) * gj4.w + bj4.w);
      }
      #pragma unroll
      for (int jj = 0; jj < 4; ++jj) {
        f16x4 w = {vb[0][jj], vb[1][jj], vb[2][jj], vb[3][jj]};
        *(f16x4*)&sB[widx[jj]] = w;
      }
    }
    __syncthreads();
    const unsigned short* pB = diag ? sA : sB;
    #pragma unroll
    for (int ks = 0; ks < 2; ++ks) {
      int rowA = wave*16 + lr;
      int cc = ks*4 + lg;
      int aoff = rowA*64 + (((cc ^ (rowA&7) ^ ((rowA>>3)&7)) & 7) << 3);
      f16x8 av = *(const f16x8*)&sA[aoff];
      #pragma unroll
      for (int n = 0; n < 4; ++n) {
        int rowB = n*16 + lr;
        int boff = rowB*64 + (((cc ^ (rowB&7) ^ ((rowB>>3)&7)) & 7) << 3);
        f16x8 bv = *(const f16x8*)&pB[boff];
        acc[n] = __builtin_amdgcn_mfma_f32_16x16x32_f16(av, bv, acc[n], 0, 0, 0);
      }
    }
    __syncthreads();
  }

  float* sC = (float*)sm;
  #pragma unroll
  for (int n = 0; n < 4; ++n)
    #pragma unroll
    for (int r = 0; r < 4; ++r)
      sC[(wave*16 + lg*4 + r)*65 + n*16 + lr] = acc[n][r];
  __syncthreads();
  unsigned short* Chb = Ch + (size_t)b*DD*DD;
  const float invTm1 = 1.f / (float)(TT - 1);
  int row = tid >> 2, cb = (tid & 3) * 16;
  int gi = i0 + row;
  unsigned short hv[16];
  #pragma unroll
  for (int e = 0; e < 16; ++e) {
    float v = sC[row*65 + cb + e] * invTm1;
    int gj = j0 + cb + e;
    if (gi == gj) v += WEPS;
    hv[e] = f2h(v);
    if (!diag) Chb[(size_t)gj*DD + gi] = hv[e];
  }
  size_t go = (size_t)gi*DD + j0 + cb;
  *(short8*)&Chb[go]     = *(short8*)&hv[0];
  *(short8*)&Chb[go + 8] = *(short8*)&hv[8];
}

// ---- K3b: power iteration in LDS (fp16 C); s = 1.12 * ||C v|| ----
__global__ __launch_bounds__(256) void power_kernel(
    const unsigned short* __restrict__ Ch, float* __restrict__ sbuf) {
  int b = blockIdx.x, tid = threadIdx.x;
  __shared__ unsigned short sC[DD*DD];   // 128 KB
  __shared__ float v[DD];
  __shared__ float red[4];
  const unsigned short* Cb = Ch + (size_t)b*DD*DD;
  #pragma unroll
  for (int i = 0; i < 32; ++i) {
    int chunkid = i*256 + tid;
    int r = chunkid >> 5, ch = chunkid & 31;
    short8 qv = *(const short8*)&Cb[(size_t)chunkid*8];
    *(short8*)&sC[r*256 + ((ch ^ (r & 7)) << 3)] = qv;
  }
  unsigned u = (unsigned)tid * 2654435761u;
  v[tid] = 0.5f + (float)((u >> 9) & 1023) * (1.f/1024.f);
  __syncthreads();
  float lam = 1.f;
  for (int it = 0; it < 10; ++it) {
    float w = 0.f;
    #pragma unroll
    for (int ch = 0; ch < 32; ++ch) {
      short8 hq = *(const short8*)&sC[tid*256 + ((ch ^ (tid & 7)) << 3)];
      const float* vp = &v[ch*8];
      #pragma unroll
      for (int e = 0; e < 8; ++e) w += h2f((unsigned short)hq[e]) * vp[e];
    }
    float ssq = w * w;
    #pragma unroll
    for (int off = 32; off; off >>= 1) ssq += __shfl_xor(ssq, off);
    if ((tid & 63) == 0) red[tid >> 6] = ssq;
    __syncthreads();
    float nrm = sqrtf(red[0] + red[1] + red[2] + red[3]);
    lam = nrm;
    v[tid] = w / nrm;
    __syncthreads();
  }
  if (tid == 0) sbuf[b] = lam * 1.12f;
}

// ---- K4: Y = C/s (in place), Z = I (fp16) ----
__global__ __launch_bounds__(256) void ns_init_kernel(unsigned short* __restrict__ Y,
    unsigned short* __restrict__ Z, const float* __restrict__ sbuf) {
  int b = blockIdx.y;
  int e = blockIdx.x * 256 + threadIdx.x;
  float invs = 1.f / sbuf[b];
  size_t idx = (size_t)b*DD*DD + e;
  Y[idx] = f2h(h2f(Y[idx]) * invs);
  bool dg = (e >> 8) == (e & 255);
  Z[idx] = dg ? (unsigned short)0x3C00 : (unsigned short)0;
}

// ---- K5: 128x128-tile fp16 MFMA GEMM, global_load_lds staging ----
__device__ __forceinline__ void bgemm_tile2(
    const unsigned short* __restrict__ A, const unsigned short* __restrict__ B,
    unsigned short* __restrict__ C,
    float alpha, float diagBeta, int tilex, int b, unsigned short* sm) {
  unsigned short* sA = sm;          // 128x64 fp16 = 16 KB
  unsigned short* sB = sm + 8192;

  const int tid = threadIdx.x;
  const int i0g = (tilex >> 1) * 128, j0g = (tilex & 1) * 128;
  const size_t mb = (size_t)b * DD * DD;
  const int wave = tid >> 6, lane = tid & 63;
  const int wr = wave >> 2, wc = wave & 3;
  const int lr = lane & 15, lg = lane >> 4;

  f32x4 acc[8] = {};

  for (int k0 = 0; k0 < DD; k0 += 64) {
    #pragma unroll
    for (int p2 = 0; p2 < 2; ++p2) {
      int slot = tid + p2 * 512;
      int row = slot >> 3, c = slot & 7;
      int srcc = (c ^ (row & 7)) << 3;             // pre-swizzled source chunk
      size_t ga = mb + (size_t)(i0g + row) * DD + k0 + srcc;
      size_t gb = mb + (size_t)(j0g + row) * DD + k0 + srcc;  // B symmetric
      int base = (wave * 64 + p2 * 512) * 8;       // wave-uniform dest
      gload16(&sA[base], A + ga);
      gload16(&sB[base], B + gb);
    }
    __syncthreads();
    #pragma unroll
    for (int ks = 0; ks < 2; ++ks) {
      int cc = ks * 4 + lg;
      f16x8 bv[2];
      #pragma unroll
      for (int n = 0; n < 2; ++n) {
        int rowB = wc * 32 + n * 16 + lr;
        int boff = rowB * 64 + ((cc ^ (rowB & 7)) * 8);
        bv[n] = *(const f16x8*)&sB[boff];
      }
      #pragma unroll
      for (int m = 0; m < 4; ++m) {
        int rowA = wr * 64 + m * 16 + lr;
        int aoff = rowA * 64 + ((cc ^ (rowA & 7)) * 8);
        f16x8 av = *(const f16x8*)&sA[aoff];
        #pragma unroll
        for (int n = 0; n < 2; ++n)
          acc[m*2+n] = __builtin_amdgcn_mfma_f32_16x16x32_f16(av, bv[n], acc[m*2+n], 0, 0, 0);
      }
    }
    __syncthreads();
  }

  #pragma unroll
  for (int m = 0; m < 4; ++m) {
    #pragma unroll
    for (int n = 0; n < 2; ++n) {
      int col = j0g + wc * 32 + n * 16 + lr;
      int row0 = i0g + wr * 64 + m * 16 + lg * 4;
      #pragma unroll
      for (int r = 0; r < 4; ++r) {
        float vv = alpha * acc[m*2+n][r];
        int row = row0 + r;
        if (row == col) vv += diagBeta;
        C[mb + (size_t)row * DD + col] = f2h(vv);
      }
    }
  }
}

__global__ __launch_bounds__(512) void bgemm_mfma2(
    const unsigned short* __restrict__ A, const unsigned short* __restrict__ B,
    unsigned short* __restrict__ C, float alpha, float diagBeta) {
  __shared__ unsigned short sm[16384];
  int flat = blockIdx.y * gridDim.x + blockIdx.x;
  int kx = flat & 7, j = flat >> 3;
  int b = (kx << 3) + (j >> 2);
  int tile = j & 3;
  bgemm_tile2(A, B, C, alpha, diagBeta, tile, b, sm);
}

__global__ __launch_bounds__(512) void bgemm_dual2(
    const unsigned short* __restrict__ A0, const unsigned short* __restrict__ B0,
    unsigned short* __restrict__ C0,
    const unsigned short* __restrict__ A1, const unsigned short* __restrict__ B1,
    unsigned short* __restrict__ C1) {
  __shared__ unsigned short sm[16384];
  int flat = blockIdx.y * gridDim.x + blockIdx.x;
  int kx = flat & 7, j = flat >> 3;
  int b = (kx << 3) + (j >> 3);
  int t8 = j & 7;
  int half = t8 >> 2, tile = t8 & 3;
  if (half == 0)
    bgemm_tile2(A0, B0, C0, 0.5f, 0.f, tile, b, sm);
  else
    bgemm_tile2(A1, B1, C1, 0.5f, 0.f, tile, b, sm);
}

// ---- K6: out = Xc @ (Z / sqrt(s)); A fp16 reg-transform, B via gload_lds ----
__global__ __launch_bounds__(256) void out_mfma(const float* __restrict__ x,
    const float* __restrict__ stats, const float* __restrict__ gamma,
    const float* __restrict__ beta, const float* __restrict__ mu,
    const unsigned short* __restrict__ Z, const float* __restrict__ sbuf,
    float* __restrict__ out) {
  int flat = blockIdx.y * gridDim.x + blockIdx.x;
  int kx = flat & 7, j = flat >> 3;
  int b = (kx << 3) + (j >> 7);
  int tile = j & 127;
  int t0 = (tile >> 2) * 64, f0 = (tile & 3) * 64;
  __shared__ unsigned short sm[8192];   // sA 64x64 fp16 8KB, sB 8KB
  unsigned short* sA = sm;
  unsigned short* sB = sm + 4096;
  __shared__ float sG[256], sBs[256];

  int tid = threadIdx.x;
  sG[tid] = gamma[tid];
  sBs[tid] = beta[tid] - mu[(size_t)b*DD + tid];
  __syncthreads();

  const int wave = tid >> 6, lane = tid & 63;
  const int lr = lane & 15, lg = lane >> 4;
  const int r0 = tid >> 3, c0 = tid & 7;
  const float* xb  = x + (size_t)b*TT*DD;
  const float* stb = stats + (size_t)b*TT*2;
  const unsigned short* Zb = Z + (size_t)b*DD*DD;

  f32x4 acc[4] = {};

  for (int k0 = 0; k0 < DD; k0 += 64) {
    #pragma unroll
    for (int p2 = 0; p2 < 2; ++p2) {
      // B (Z fp16) via async gload: linear dest, pre-swizzled source
      int slot = tid + p2 * 256;
      int rowb = slot >> 3, cb2 = slot & 7;
      int srcc = (cb2 ^ (rowb & 7)) << 3;
      size_t gz = (size_t)(f0 + rowb) * DD + k0 + srcc;
      int base = (wave * 64 + p2 * 256) * 8;
      gload16(&sB[base], Zb + gz);
      // A (Xc fp16) transform + swizzled vector write
      int row = r0 + p2 * 32;
      int trow = t0 + row;
      float mean = stb[2*trow], rstd = stb[2*trow+1];
      const float* xr = xb + (size_t)trow*DD + k0 + c0*8;
      _Float16 h8[8];
      #pragma unroll
      for (int qq = 0; qq < 2; ++qq) {
        float4 v = *(const float4*)&xr[qq*4];
        float vv[4] = {v.x, v.y, v.z, v.w};
        #pragma unroll
        for (int e2 = 0; e2 < 4; ++e2) {
          int d = k0 + c0*8 + qq*4 + e2;
          h8[qq*4+e2] = (_Float16)((vv[e2] - mean) * rstd * sG[d] + sBs[d]);
        }
      }
      int ld = row * 64 + ((c0 ^ (row & 7)) * 8);
      *(f16x8*)&sA[ld] = *(f16x8*)&h8[0];
    }
    __syncthreads();
    #pragma unroll
    for (int ks = 0; ks < 2; ++ks) {
      int rowA = wave * 16 + lr;
      int cc = ks * 4 + lg;
      int aoff = rowA * 64 + ((cc ^ (rowA & 7)) * 8);
      f16x8 av = *(const f16x8*)&sA[aoff];
      #pragma unroll
      for (int n = 0; n < 4; ++n) {
        int rowB = n * 16 + lr;
        int boff = rowB * 64 + ((cc ^ (rowB & 7)) * 8);
        f16x8 bv = *(const f16x8*)&sB[boff];
        acc[n] = __builtin_amdgcn_mfma_f32_16x16x32_f16(av, bv, acc[n], 0, 0, 0);
      }
    }
    __syncthreads();
  }

  float rs = rsqrtf(sbuf[b]);
  float* ob = out + (size_t)b*TT*DD;
  #pragma unroll
  for (int n = 0; n < 4; ++n)
    #pragma unroll
    for (int r = 0; r < 4; ++r)
      ob[(size_t)(t0 + wave*16 + lg*4 + r)*DD + f0 + n*16 + lr] = acc[n][r] * rs;
}

extern "C" void kernel_launch(void* const* d_in, const int* in_sizes, int n_in,
                              void* d_out, int out_size, void* d_ws, size_t ws_size,
                              hipStream_t stream) {
  const float* x     = (const float*)d_in[0];
  const float* gamma = (const float*)d_in[1];
  const float* beta  = (const float*)d_in[2];
  float* out = (float*)d_out;

  float* wsf   = (float*)d_ws;
  float* stats = wsf;                      // 262144 floats
  float* mu    = wsf + 262144;             // 16384
  float* sbuf  = wsf + 278528;             // 64
  unsigned short* nsb = (unsigned short*)(wsf + 278784);
  const size_t MATU = (size_t)BB * DD * DD;      // 4194304 ushorts per plane
  unsigned short* H[5];
  for (int k = 0; k < 5; ++k) H[k] = nsb + (size_t)k * MATU;
  float* part = (float*)H[4];              // aliased: dead before buffer-4 first write

  prepass_kernel<<<dim3(16, BB), 256, 0, stream>>>(x, stats, part);
  mu_finalize_kernel<<<BB, 256, 0, stream>>>(part, gamma, beta, mu);
  cov_mfma<<<dim3(10, BB), 256, 0, stream>>>(x, stats, gamma, beta, mu, H[0]);
  power_kernel<<<BB, 256, 0, stream>>>(H[0], sbuf);
  ns_init_kernel<<<dim3(256, BB), 256, 0, stream>>>(H[0], H[1], sbuf);

  int y = 0, z = 1, m = 2, s = 3, u = 4;
  for (int it = 0; it < NS_ITERS - 1; ++it) {
    bgemm_mfma2<<<dim3(4, BB), 512, 0, stream>>>(H[z], H[y], H[m], -1.f, 3.f);
    bgemm_dual2<<<dim3(8, BB), 512, 0, stream>>>(H[y], H[m], H[s], H[m], H[z], H[u]);
    int oy = y, oz = z;
    y = s; z = u; s = oy; u = oz;
  }
  bgemm_mfma2<<<dim3(4, BB), 512, 0, stream>>>(H[z], H[y], H[m], -1.f, 3.f);
  bgemm_mfma2<<<dim3(4, BB), 512, 0, stream>>>(H[m], H[z], H[s], 0.5f, 0.f);
  z = s;

  out_mfma<<<dim3(128, BB), 256, 0, stream>>>(x, stats, gamma, beta, mu, H[z], sbuf, out);
}

// Round 9
// 237.291 us; speedup vs baseline: 12.0474x; 1.1636x over previous
//
#include <hip/hip_runtime.h>
#include <cstddef>

#define TT 2048
#define BB 64
#define DD 256
#define LN_EPS 1e-5f
#define WEPS 1e-4f

typedef __attribute__((ext_vector_type(8))) short short8;
typedef __attribute__((ext_vector_type(4))) float f32x4;
typedef __attribute__((ext_vector_type(8))) _Float16 f16x8;
typedef __attribute__((ext_vector_type(4))) _Float16 f16x4;

__device__ __forceinline__ unsigned short f2h(float f) {
  _Float16 h = (_Float16)f;
  return *(unsigned short*)&h;
}
__device__ __forceinline__ float h2f(unsigned short u) {
  _Float16 h = *(_Float16*)&u;
  return (float)h;
}
// async global->LDS, 16B/lane; dest wave-uniform base (+lane*16 by HW)
__device__ __forceinline__ void gload16(unsigned short* lds, const unsigned short* g) {
  __builtin_amdgcn_global_load_lds(
      (const __attribute__((address_space(1))) void*)g,
      (__attribute__((address_space(3))) void*)lds, 16, 0, 0);
}

// ---- K1: fused LN stats + column partial sums (single x pass) ----
__global__ __launch_bounds__(256) void prepass_kernel(const float* __restrict__ x,
    float* __restrict__ stats, float* __restrict__ part) {
  int c = blockIdx.x;
  int b = blockIdx.y;
  int tid = threadIdx.x;
  int wave = tid >> 6, lane = tid & 63;
  int rowbase = b * TT + c * 128 + wave * 32;
  const float* xb = x + (size_t)rowbase * DD + lane * 4;
  float a0 = 0.f, a1 = 0.f, a2 = 0.f, a3 = 0.f;
  for (int i = 0; i < 32; ++i) {
    float4 v = *(const float4*)&xb[(size_t)i * DD];
    float s  = v.x + v.y + v.z + v.w;
    float sq = v.x*v.x + v.y*v.y + v.z*v.z + v.w*v.w;
    #pragma unroll
    for (int off = 32; off; off >>= 1) { s += __shfl_xor(s, off); sq += __shfl_xor(sq, off); }
    float mean = s * (1.f/DD);
    float var  = fmaxf(sq * (1.f/DD) - mean*mean, 0.f);
    float rstd = rsqrtf(var + LN_EPS);
    if (lane == 0) {
      stats[2*(rowbase+i)]   = mean;
      stats[2*(rowbase+i)+1] = rstd;
    }
    a0 += (v.x - mean) * rstd;
    a1 += (v.y - mean) * rstd;
    a2 += (v.z - mean) * rstd;
    a3 += (v.w - mean) * rstd;
  }
  int pidx = c * 4 + wave;
  *(float4*)&part[((size_t)pidx*BB + b)*DD + lane*4] = make_float4(a0, a1, a2, a3);
}

__global__ __launch_bounds__(256) void mu_finalize_kernel(const float* __restrict__ part,
                                                          const float* __restrict__ gamma,
                                                          const float* __restrict__ beta,
                                                          float* __restrict__ mu) {
  int b = blockIdx.x;
  int d = threadIdx.x;
  float s = 0.f;
  #pragma unroll 8
  for (int c = 0; c < 64; ++c) s += part[((size_t)c*BB + b)*DD + d];
  mu[b*DD + d] = gamma[d] * s * (1.f/TT) + beta[d];
}

// ---- K3: cov via fp16 MFMA: C = Gram(Xc^T)/(T-1) + eps I -> fp16 plane ----
__global__ __launch_bounds__(256) void cov_mfma(const float* __restrict__ x,
    const float* __restrict__ stats, const float* __restrict__ gamma,
    const float* __restrict__ beta, const float* __restrict__ mu,
    unsigned short* __restrict__ Ch) {
  int flat = blockIdx.y * gridDim.x + blockIdx.x;  // [0,640); XCD-bijective remap
  int kx = flat & 7, j = flat >> 3;
  int b = (kx << 3) + j / 10;
  int tile = j - (j / 10) * 10;
  int p = 0, t = tile;
  while (t >= 4 - p) { t -= (4 - p); ++p; }
  int q = p + t;
  int i0 = p * 64, j0 = q * 64;
  bool diag = (p == q);

  __shared__ unsigned short sm[8448];
  unsigned short* sA = sm;
  unsigned short* sB = sm + 4096;
  __shared__ float sGi[64], sBi[64], sGj[64], sBj[64];

  int tid = threadIdx.x;
  const float* mub = mu + (size_t)b*DD;
  if (tid < 64) {
    sGi[tid] = gamma[i0+tid]; sBi[tid] = beta[i0+tid] - mub[i0+tid];
    sGj[tid] = gamma[j0+tid]; sBj[tid] = beta[j0+tid] - mub[j0+tid];
  }
  __syncthreads();

  int wave = tid >> 6, lane = tid & 63;
  int lr = lane & 15, lg = lane >> 4;
  int tg4 = tid >> 4;
  int dg  = tid & 15;
  int d0 = dg * 4;
  const float* xb  = x + (size_t)b*TT*DD;
  const float* stb = stats + (size_t)b*TT*2;

  float4 gi4 = *(const float4*)&sGi[d0];
  float4 bi4 = *(const float4*)&sBi[d0];
  float4 gj4 = *(const float4*)&sGj[d0];
  float4 bj4 = *(const float4*)&sBj[d0];

  int ch16 = tg4 >> 1, half = tg4 & 1;
  int widx[4];
  #pragma unroll
  for (int jj = 0; jj < 4; ++jj) {
    int dl = d0 + jj;
    int swz = (ch16 ^ (dl & 7) ^ ((dl >> 3) & 7)) & 7;
    widx[jj] = dl*64 + swz*8 + half*4;
  }

  f32x4 acc[4] = {};

  for (int k0 = 0; k0 < TT; k0 += 64) {
    int trow = k0 + tg4 * 4;
    float4 s01 = *(const float4*)&stb[2*trow];
    float4 s23 = *(const float4*)&stb[2*trow + 4];
    float mm[4] = {s01.x, s01.z, s23.x, s23.z};
    float rr[4] = {s01.y, s01.w, s23.y, s23.w};
    {
      _Float16 va[4][4];
      #pragma unroll
      for (int i = 0; i < 4; ++i) {
        float4 v = *(const float4*)&xb[(size_t)(trow+i)*DD + i0 + d0];
        va[i][0] = (_Float16)(((v.x - mm[i]) * rr[i]) * gi4.x + bi4.x);
        va[i][1] = (_Float16)(((v.y - mm[i]) * rr[i]) * gi4.y + bi4.y);
        va[i][2] = (_Float16)(((v.z - mm[i]) * rr[i]) * gi4.z + bi4.z);
        va[i][3] = (_Float16)(((v.w - mm[i]) * rr[i]) * gi4.w + bi4.w);
      }
      #pragma unroll
      for (int jj = 0; jj < 4; ++jj) {
        f16x4 w = {va[0][jj], va[1][jj], va[2][jj], va[3][jj]};
        *(f16x4*)&sA[widx[jj]] = w;
      }
    }
    if (!diag) {
      _Float16 vb[4][4];
      #pragma unroll
      for (int i = 0; i < 4; ++i) {
        float4 v = *(const float4*)&xb[(size_t)(trow+i)*DD + j0 + d0];
        vb[i][0] = (_Float16)(((v.x - mm[i]) * rr[i]) * gj4.x + bj4.x);
        vb[i][1] = (_Float16)(((v.y - mm[i]) * rr[i]) * gj4.y + bj4.y);
        vb[i][2] = (_Float16)(((v.z - mm[i]) * rr[i]) * gj4.z + bj4.z);
        vb[i][3] = (_Float16)(((v.w - mm[i]) * rr[i]) * gj4.w + bj4.w);
      }
      #pragma unroll
      for (int jj = 0; jj < 4; ++jj) {
        f16x4 w = {vb[0][jj], vb[1][jj], vb[2][jj], vb[3][jj]};
        *(f16x4*)&sB[widx[jj]] = w;
      }
    }
    __syncthreads();
    const unsigned short* pB = diag ? sA : sB;
    #pragma unroll
    for (int ks = 0; ks < 2; ++ks) {
      int rowA = wave*16 + lr;
      int cc = ks*4 + lg;
      int aoff = rowA*64 + (((cc ^ (rowA&7) ^ ((rowA>>3)&7)) & 7) << 3);
      f16x8 av = *(const f16x8*)&sA[aoff];
      #pragma unroll
      for (int n = 0; n < 4; ++n) {
        int rowB = n*16 + lr;
        int boff = rowB*64 + (((cc ^ (rowB&7) ^ ((rowB>>3)&7)) & 7) << 3);
        f16x8 bv = *(const f16x8*)&pB[boff];
        acc[n] = __builtin_amdgcn_mfma_f32_16x16x32_f16(av, bv, acc[n], 0, 0, 0);
      }
    }
    __syncthreads();
  }

  float* sC = (float*)sm;
  #pragma unroll
  for (int n = 0; n < 4; ++n)
    #pragma unroll
    for (int r = 0; r < 4; ++r)
      sC[(wave*16 + lg*4 + r)*65 + n*16 + lr] = acc[n][r];
  __syncthreads();
  unsigned short* Chb = Ch + (size_t)b*DD*DD;
  const float invTm1 = 1.f / (float)(TT - 1);
  int row = tid >> 2, cb = (tid & 3) * 16;
  int gi = i0 + row;
  unsigned short hv[16];
  #pragma unroll
  for (int e = 0; e < 16; ++e) {
    float v = sC[row*65 + cb + e] * invTm1;
    int gj = j0 + cb + e;
    if (gi == gj) v += WEPS;
    hv[e] = f2h(v);
    if (!diag) Chb[(size_t)gj*DD + gi] = hv[e];
  }
  size_t go = (size_t)gi*DD + j0 + cb;
  *(short8*)&Chb[go]     = *(short8*)&hv[0];
  *(short8*)&Chb[go + 8] = *(short8*)&hv[8];
}

// ---- K3b: power iteration in LDS (fp16 C); s = 1.12 * ||C v|| ----
__global__ __launch_bounds__(256) void power_kernel(
    const unsigned short* __restrict__ Ch, float* __restrict__ sbuf) {
  int b = blockIdx.x, tid = threadIdx.x;
  __shared__ unsigned short sC[DD*DD];   // 128 KB
  __shared__ float v[DD];
  __shared__ float red[4];
  const unsigned short* Cb = Ch + (size_t)b*DD*DD;
  #pragma unroll
  for (int i = 0; i < 32; ++i) {
    int chunkid = i*256 + tid;
    int r = chunkid >> 5, ch = chunkid & 31;
    short8 qv = *(const short8*)&Cb[(size_t)chunkid*8];
    *(short8*)&sC[r*256 + ((ch ^ (r & 7)) << 3)] = qv;
  }
  unsigned u = (unsigned)tid * 2654435761u;
  v[tid] = 0.5f + (float)((u >> 9) & 1023) * (1.f/1024.f);
  __syncthreads();
  float lam = 1.f;
  for (int it = 0; it < 10; ++it) {
    float w = 0.f;
    #pragma unroll
    for (int ch = 0; ch < 32; ++ch) {
      short8 hq = *(const short8*)&sC[tid*256 + ((ch ^ (tid & 7)) << 3)];
      const float* vp = &v[ch*8];
      #pragma unroll
      for (int e = 0; e < 8; ++e) w += h2f((unsigned short)hq[e]) * vp[e];
    }
    float ssq = w * w;
    #pragma unroll
    for (int off = 32; off; off >>= 1) ssq += __shfl_xor(ssq, off);
    if ((tid & 63) == 0) red[tid >> 6] = ssq;
    __syncthreads();
    float nrm = sqrtf(red[0] + red[1] + red[2] + red[3]);
    lam = nrm;
    v[tid] = w / nrm;
    __syncthreads();
  }
  if (tid == 0) sbuf[b] = lam * 1.12f;
}

// ---- K4: elementwise first NS iteration: M1 = 3I - C/s ; Z1 = 1.5I - 0.5C/s ----
__global__ __launch_bounds__(256) void ew1_kernel(const unsigned short* __restrict__ C,
    unsigned short* __restrict__ M1, unsigned short* __restrict__ Z1,
    const float* __restrict__ sbuf) {
  int b = blockIdx.y;
  int chunk = blockIdx.x * 256 + threadIdx.x;   // 0..8191
  int row = chunk >> 5, cb = (chunk & 31) * 8;
  float inv = 1.f / sbuf[b];
  size_t off = (size_t)b*DD*DD + (size_t)chunk*8;
  short8 cv = *(const short8*)&C[off];
  unsigned short mo[8], zo[8];
  #pragma unroll
  for (int e = 0; e < 8; ++e) {
    float c = h2f((unsigned short)cv[e]) * inv;
    float dg = (row == cb + e) ? 1.f : 0.f;
    mo[e] = f2h(3.f*dg - c);
    zo[e] = f2h(1.5f*dg - 0.5f*c);
  }
  *(short8*)&M1[off] = *(short8*)&mo[0];
  *(short8*)&Z1[off] = *(short8*)&zo[0];
}

// ---- K5: 128x128-tile fp16 MFMA GEMM body, global_load_lds staging ----
__device__ __forceinline__ void bgemm_tile2(
    const unsigned short* __restrict__ A, const unsigned short* __restrict__ B,
    unsigned short* __restrict__ C,
    float alpha, float diagBeta, int tilex, int b, unsigned short* sm) {
  unsigned short* sA = sm;          // 128x64 fp16 = 16 KB
  unsigned short* sB = sm + 8192;

  const int tid = threadIdx.x;
  const int i0g = (tilex >> 1) * 128, j0g = (tilex & 1) * 128;
  const size_t mb = (size_t)b * DD * DD;
  const int wave = tid >> 6, lane = tid & 63;
  const int wr = wave >> 2, wc = wave & 3;
  const int lr = lane & 15, lg = lane >> 4;

  f32x4 acc[8] = {};

  for (int k0 = 0; k0 < DD; k0 += 64) {
    #pragma unroll
    for (int p2 = 0; p2 < 2; ++p2) {
      int slot = tid + p2 * 512;
      int row = slot >> 3, c = slot & 7;
      int srcc = (c ^ (row & 7)) << 3;             // pre-swizzled source chunk
      size_t ga = mb + (size_t)(i0g + row) * DD + k0 + srcc;
      size_t gb = mb + (size_t)(j0g + row) * DD + k0 + srcc;  // B symmetric
      int base = (wave * 64 + p2 * 512) * 8;       // wave-uniform dest
      gload16(&sA[base], A + ga);
      gload16(&sB[base], B + gb);
    }
    __syncthreads();
    #pragma unroll
    for (int ks = 0; ks < 2; ++ks) {
      int cc = ks * 4 + lg;
      f16x8 bv[2];
      #pragma unroll
      for (int n = 0; n < 2; ++n) {
        int rowB = wc * 32 + n * 16 + lr;
        int boff = rowB * 64 + ((cc ^ (rowB & 7)) * 8);
        bv[n] = *(const f16x8*)&sB[boff];
      }
      #pragma unroll
      for (int m = 0; m < 4; ++m) {
        int rowA = wr * 64 + m * 16 + lr;
        int aoff = rowA * 64 + ((cc ^ (rowA & 7)) * 8);
        f16x8 av = *(const f16x8*)&sA[aoff];
        #pragma unroll
        for (int n = 0; n < 2; ++n)
          acc[m*2+n] = __builtin_amdgcn_mfma_f32_16x16x32_f16(av, bv[n], acc[m*2+n], 0, 0, 0);
      }
    }
    __syncthreads();
  }

  #pragma unroll
  for (int m = 0; m < 4; ++m) {
    #pragma unroll
    for (int n = 0; n < 2; ++n) {
      int col = j0g + wc * 32 + n * 16 + lr;
      int row0 = i0g + wr * 64 + m * 16 + lg * 4;
      #pragma unroll
      for (int r = 0; r < 4; ++r) {
        float vv = alpha * acc[m*2+n][r];
        int row = row0 + r;
        if (row == col) vv += diagBeta;
        C[mb + (size_t)row * DD + col] = f2h(vv);
      }
    }
  }
}

__global__ __launch_bounds__(512) void bgemm_mfma2(
    const unsigned short* __restrict__ A, const unsigned short* __restrict__ B,
    unsigned short* __restrict__ C, float alpha, float diagBeta) {
  __shared__ unsigned short sm[16384];
  int flat = blockIdx.y * gridDim.x + blockIdx.x;
  int kx = flat & 7, j = flat >> 3;
  int b = (kx << 3) + (j >> 2);
  int tile = j & 3;
  bgemm_tile2(A, B, C, alpha, diagBeta, tile, b, sm);
}

// Y1 = (0.5/s) * C * M1  (dynamic per-batch alpha)
__global__ __launch_bounds__(512) void bgemm_y1(
    const unsigned short* __restrict__ A, const unsigned short* __restrict__ B,
    unsigned short* __restrict__ C, const float* __restrict__ sbuf) {
  __shared__ unsigned short sm[16384];
  int flat = blockIdx.y * gridDim.x + blockIdx.x;
  int kx = flat & 7, j = flat >> 3;
  int b = (kx << 3) + (j >> 2);
  int tile = j & 3;
  float alpha = 0.5f / sbuf[b];
  bgemm_tile2(A, B, C, alpha, 0.f, tile, b, sm);
}

__global__ __launch_bounds__(512) void bgemm_dual2(
    const unsigned short* __restrict__ A0, const unsigned short* __restrict__ B0,
    unsigned short* __restrict__ C0,
    const unsigned short* __restrict__ A1, const unsigned short* __restrict__ B1,
    unsigned short* __restrict__ C1) {
  __shared__ unsigned short sm[16384];
  int flat = blockIdx.y * gridDim.x + blockIdx.x;
  int kx = flat & 7, j = flat >> 3;
  int b = (kx << 3) + (j >> 3);
  int t8 = j & 7;
  int half = t8 >> 2, tile = t8 & 3;
  if (half == 0)
    bgemm_tile2(A0, B0, C0, 0.5f, 0.f, tile, b, sm);
  else
    bgemm_tile2(A1, B1, C1, 0.5f, 0.f, tile, b, sm);
}

// ---- K6: out = Xc @ (Z / sqrt(s)); 128x128 tile, 512 thr ----
__global__ __launch_bounds__(512) void out_mfma2(const float* __restrict__ x,
    const float* __restrict__ stats, const float* __restrict__ gamma,
    const float* __restrict__ beta, const float* __restrict__ mu,
    const unsigned short* __restrict__ Z, const float* __restrict__ sbuf,
    float* __restrict__ out) {
  int flat = blockIdx.y * gridDim.x + blockIdx.x;  // [0,2048)
  int kx = flat & 7, j = flat >> 3;                // j in [0,256)
  int b = (kx << 3) + (j >> 5);
  int tile = j & 31;                               // 16 t-tiles x 2 f-tiles
  int t0 = (tile >> 1) * 128, f0 = (tile & 1) * 128;
  __shared__ unsigned short sm[16384];             // sA 16KB + sB 16KB
  unsigned short* sA = sm;
  unsigned short* sB = sm + 8192;
  __shared__ float sG[256], sBs[256];

  int tid = threadIdx.x;
  if (tid < 256) {
    sG[tid] = gamma[tid];
    sBs[tid] = beta[tid] - mu[(size_t)b*DD + tid];
  } else {
    int d = tid - 256;
    // second half loads nothing extra; fill remaining
    (void)d;
  }
  if (tid >= 256) {
    // ensure full 256-entry fill from the other half too (no-op)
  }
  __syncthreads();

  const int wave = tid >> 6, lane = tid & 63;
  const int wr = wave >> 2, wc = wave & 3;
  const int lr = lane & 15, lg = lane >> 4;
  const float* xb  = x + (size_t)b*TT*DD;
  const float* stb = stats + (size_t)b*TT*2;
  const unsigned short* Zb = Z + (size_t)b*DD*DD;

  f32x4 acc[8] = {};

  for (int k0 = 0; k0 < DD; k0 += 64) {
    #pragma unroll
    for (int p2 = 0; p2 < 2; ++p2) {
      int slot = tid + p2 * 512;
      int row = slot >> 3, c0 = slot & 7;
      // B (Z fp16): gload, linear dest, pre-swizzled source
      int srcc = (c0 ^ (row & 7)) << 3;
      size_t gz = (size_t)(f0 + row) * DD + k0 + srcc;
      int base = (wave * 64 + p2 * 512) * 8;
      gload16(&sB[base], Zb + gz);
      // A (Xc fp16): transform + swizzled vector write
      int trow = t0 + row;
      float mean = stb[2*trow], rstd = stb[2*trow+1];
      const float* xr = xb + (size_t)trow*DD + k0 + c0*8;
      _Float16 h8[8];
      #pragma unroll
      for (int qq = 0; qq < 2; ++qq) {
        float4 v = *(const float4*)&xr[qq*4];
        float vv[4] = {v.x, v.y, v.z, v.w};
        #pragma unroll
        for (int e2 = 0; e2 < 4; ++e2) {
          int d = k0 + c0*8 + qq*4 + e2;
          h8[qq*4+e2] = (_Float16)((vv[e2] - mean) * rstd * sG[d] + sBs[d]);
        }
      }
      int ld = row * 64 + ((c0 ^ (row & 7)) * 8);
      *(f16x8*)&sA[ld] = *(f16x8*)&h8[0];
    }
    __syncthreads();
    #pragma unroll
    for (int ks = 0; ks < 2; ++ks) {
      int cc = ks * 4 + lg;
      f16x8 bv[2];
      #pragma unroll
      for (int n = 0; n < 2; ++n) {
        int rowB = wc * 32 + n * 16 + lr;
        int boff = rowB * 64 + ((cc ^ (rowB & 7)) * 8);
        bv[n] = *(const f16x8*)&sB[boff];
      }
      #pragma unroll
      for (int m = 0; m < 4; ++m) {
        int rowA = wr * 64 + m * 16 + lr;
        int aoff = rowA * 64 + ((cc ^ (rowA & 7)) * 8);
        f16x8 av = *(const f16x8*)&sA[aoff];
        #pragma unroll
        for (int n = 0; n < 2; ++n)
          acc[m*2+n] = __builtin_amdgcn_mfma_f32_16x16x32_f16(av, bv[n], acc[m*2+n], 0, 0, 0);
      }
    }
    __syncthreads();
  }

  float rs = rsqrtf(sbuf[b]);
  float* ob = out + (size_t)b*TT*DD;
  #pragma unroll
  for (int m = 0; m < 4; ++m) {
    #pragma unroll
    for (int n = 0; n < 2; ++n) {
      int col = f0 + wc * 32 + n * 16 + lr;
      int row0 = t0 + wr * 64 + m * 16 + lg * 4;
      #pragma unroll
      for (int r = 0; r < 4; ++r)
        ob[(size_t)(row0 + r)*DD + col] = acc[m*2+n][r] * rs;
    }
  }
}

extern "C" void kernel_launch(void* const* d_in, const int* in_sizes, int n_in,
                              void* d_out, int out_size, void* d_ws, size_t ws_size,
                              hipStream_t stream) {
  const float* x     = (const float*)d_in[0];
  const float* gamma = (const float*)d_in[1];
  const float* beta  = (const float*)d_in[2];
  float* out = (float*)d_out;

  float* wsf   = (float*)d_ws;
  float* stats = wsf;                      // 262144 floats (1 MB)
  float* mu    = wsf + 262144;             // 16384
  float* sbuf  = wsf + 278528;             // 64
  unsigned short* nsb = (unsigned short*)(wsf + 278784);
  const size_t MATU = (size_t)BB * DD * DD;      // 4194304 ushorts (8 MB) per plane
  unsigned short* H[5];
  for (int k = 0; k < 5; ++k) H[k] = nsb + (size_t)k * MATU;
  // part (16 MB) aliased onto H1+H2 (both first written at ew1, after mu_finalize)
  float* part = (float*)H[1];

  prepass_kernel<<<dim3(16, BB), 256, 0, stream>>>(x, stats, part);
  mu_finalize_kernel<<<BB, 256, 0, stream>>>(part, gamma, beta, mu);
  cov_mfma<<<dim3(10, BB), 256, 0, stream>>>(x, stats, gamma, beta, mu, H[0]);
  power_kernel<<<BB, 256, 0, stream>>>(H[0], sbuf);

  // it1 (algebraic): M1 = 3I - C/s (H2); Z1 = 1.5I - 0.5C/s (H1); Y1 = (0.5/s) C M1 (H3)
  ew1_kernel<<<dim3(32, BB), 256, 0, stream>>>(H[0], H[2], H[1], sbuf);
  bgemm_y1<<<dim3(4, BB), 512, 0, stream>>>(H[0], H[2], H[3], sbuf);

  // it2: M2 = 3I - Z1 Y1 (H2); Y2 = 0.5 Y1 M2 (H0); Z2 = 0.5 M2 Z1 (H4)
  bgemm_mfma2<<<dim3(4, BB), 512, 0, stream>>>(H[1], H[3], H[2], -1.f, 3.f);
  bgemm_dual2<<<dim3(8, BB), 512, 0, stream>>>(H[3], H[2], H[0], H[2], H[1], H[4]);
  // it3: M3 (H2); Y3 (H3); Z3 (H1)
  bgemm_mfma2<<<dim3(4, BB), 512, 0, stream>>>(H[4], H[0], H[2], -1.f, 3.f);
  bgemm_dual2<<<dim3(8, BB), 512, 0, stream>>>(H[0], H[2], H[3], H[2], H[4], H[1]);
  // it4: M4 (H2); Y4 (H0); Z4 (H4)
  bgemm_mfma2<<<dim3(4, BB), 512, 0, stream>>>(H[1], H[3], H[2], -1.f, 3.f);
  bgemm_dual2<<<dim3(8, BB), 512, 0, stream>>>(H[3], H[2], H[0], H[2], H[1], H[4]);
  // it5 (Z only): M5 (H2); Z5 = 0.5 M5 Z4 (H1)
  bgemm_mfma2<<<dim3(4, BB), 512, 0, stream>>>(H[4], H[0], H[2], -1.f, 3.f);
  bgemm_mfma2<<<dim3(4, BB), 512, 0, stream>>>(H[2], H[4], H[1], 0.5f, 0.f);

  out_mfma2<<<dim3(32, BB), 512, 0, stream>>>(x, stats, gamma, beta, mu, H[1], sbuf, out);
}